// Round 1
// baseline (1048.996 us; speedup 1.0000x reference)
//
#include <hip/hip_runtime.h>
#include <cstdint>

// ---------------------------------------------------------------------------
// BotRGCN: embed -> RGCN(2 rel) -> RGCN(2 rel) -> linear
// Structure: CSR build by (rel,dst) once per launch, then gather-based mean
// aggregation (no float atomics), fused K=384 GEMM per RGCN layer.
// All fp32 (reference dtype). Round 0: correctness-first baseline.
// ---------------------------------------------------------------------------

// ---- feature pre-embed: h_pre[n,k] = leaky(x_num@W_num+b | x_cat@W_cat+b) ----
__global__ __launch_bounds__(256) void k_pre(
    const float* __restrict__ x,
    const float* __restrict__ Wnum, const float* __restrict__ bnum,
    const float* __restrict__ Wcat, const float* __restrict__ bcat,
    float* __restrict__ hpre, int N)
{
    int gid = blockIdx.x * 256 + threadIdx.x;
    if (gid >= N * 128) return;
    int n = gid >> 7, k = gid & 127;
    const float* xr = x + n * 8;
    float acc;
    if (k < 64) {
        acc = bnum[k];
        #pragma unroll
        for (int p = 0; p < 5; ++p) acc += xr[p] * Wnum[p * 64 + k];
    } else {
        int kk = k - 64;
        acc = bcat[kk];
        #pragma unroll
        for (int p = 0; p < 3; ++p) acc += xr[5 + p] * Wcat[p * 64 + kk];
    }
    hpre[gid] = acc >= 0.f ? acc : 0.01f * acc;
}

// ---- CSR build ----
__global__ __launch_bounds__(256) void k_count(
    const int* __restrict__ ei, const int* __restrict__ et,
    int* __restrict__ deg, int E, int N)
{
    int e = blockIdx.x * 256 + threadIdx.x;
    if (e >= E) return;
    int r = et[e], d = ei[E + e];
    atomicAdd(&deg[r * N + d], 1);
}

__global__ __launch_bounds__(256) void k_scan1(
    const int* __restrict__ deg, int* __restrict__ off,
    int* __restrict__ bsum, int n)
{
    __shared__ int s[256];
    int t = threadIdx.x;
    int i = blockIdx.x * 256 + t;
    int v = (i < n) ? deg[i] : 0;
    s[t] = v;
    __syncthreads();
    #pragma unroll
    for (int d = 1; d < 256; d <<= 1) {
        int add = (t >= d) ? s[t - d] : 0;
        __syncthreads();
        s[t] += add;
        __syncthreads();
    }
    if (i < n) off[i] = s[t] - v;           // exclusive within block
    if (t == 255) bsum[blockIdx.x] = s[255]; // block total
}

__global__ __launch_bounds__(1024) void k_scan2(int* __restrict__ bsum, int nb)
{
    __shared__ int s[1024];
    int t = threadIdx.x;
    int v = (t < nb) ? bsum[t] : 0;
    s[t] = v;
    __syncthreads();
    #pragma unroll
    for (int d = 1; d < 1024; d <<= 1) {
        int add = (t >= d) ? s[t - d] : 0;
        __syncthreads();
        s[t] += add;
        __syncthreads();
    }
    if (t < nb) bsum[t] = s[t] - v;          // exclusive block offsets
}

__global__ __launch_bounds__(256) void k_scan3(
    int* __restrict__ off, const int* __restrict__ bsum, int n)
{
    int i = blockIdx.x * 256 + threadIdx.x;
    if (i < n) off[i] += bsum[blockIdx.x];
}

__global__ __launch_bounds__(256) void k_fill(
    const int* __restrict__ ei, const int* __restrict__ et,
    const int* __restrict__ off, int* __restrict__ cur,
    int* __restrict__ esrc, int E, int N)
{
    int e = blockIdx.x * 256 + threadIdx.x;
    if (e >= E) return;
    int r = et[e], d = ei[E + e], s = ei[e];
    int i = r * N + d;
    int pos = off[i] + atomicAdd(&cur[i], 1);
    esrc[pos] = s;
}

// ---- mean aggregation: one block per (rel,node) segment, f = threadIdx ----
__global__ __launch_bounds__(128) void k_gather(
    const float* __restrict__ h, const int* __restrict__ esrc,
    const int* __restrict__ off, const int* __restrict__ deg,
    float* __restrict__ agg)
{
    int i = blockIdx.x;
    int f = threadIdx.x;
    int cnt = deg[i], st = off[i];
    float s0 = 0.f, s1 = 0.f, s2 = 0.f, s3 = 0.f;
    int e = 0;
    for (; e + 4 <= cnt; e += 4) {
        int i0 = esrc[st + e + 0];
        int i1 = esrc[st + e + 1];
        int i2 = esrc[st + e + 2];
        int i3 = esrc[st + e + 3];
        s0 += h[i0 * 128 + f];
        s1 += h[i1 * 128 + f];
        s2 += h[i2 * 128 + f];
        s3 += h[i3 * 128 + f];
    }
    for (; e < cnt; ++e) s0 += h[esrc[st + e] * 128 + f];
    float s = (s0 + s1) + (s2 + s3);
    float inv = 1.0f / (float)(cnt > 1 ? cnt : 1);
    agg[i * 128 + f] = s * inv;
}

// ---- generic fp32 GEMM: C[M,128] = act( sum_p A_p[M,128] @ B_p[128,128] + bias )
// Up to 3 (A,B) parts (K=128 each). act: prelu_a != null -> PReLU.
// Tile: BM=64 nodes x BN=128 feats, 256 threads, thread = 8 nodes x 4 feats.
__global__ __launch_bounds__(256) void k_gemm(
    const float* __restrict__ A0, const float* __restrict__ B0,
    const float* __restrict__ A1, const float* __restrict__ B1,
    const float* __restrict__ A2, const float* __restrict__ B2,
    const float* __restrict__ bias, const float* __restrict__ prelu_a,
    float* __restrict__ C, int M)
{
    __shared__ float As[64 * 20];   // pad 16 -> 20 floats/row (16B-aligned rows)
    __shared__ float Bs[16 * 128];
    int t = threadIdx.x;
    int tx = t & 31;        // feature group: j = tx*4 .. tx*4+3
    int ty = t >> 5;        // node group:   m = ty*8 .. ty*8+7
    int m0 = blockIdx.x * 64;

    float acc[8][4];
    #pragma unroll
    for (int i = 0; i < 8; ++i)
        #pragma unroll
        for (int c = 0; c < 4; ++c) acc[i][c] = 0.f;

    const float* Ap[3] = {A0, A1, A2};
    const float* Bp[3] = {B0, B1, B2};

    for (int p = 0; p < 3; ++p) {
        const float* A = Ap[p];
        const float* B = Bp[p];
        if (!A) continue;
        for (int kt = 0; kt < 8; ++kt) {
            // stage A tile (64 x 16)
            {
                int node = t >> 2, kc = t & 3;
                int gmn = m0 + node;
                float4 v = make_float4(0.f, 0.f, 0.f, 0.f);
                if (gmn < M)
                    v = *(const float4*)(A + (size_t)gmn * 128 + kt * 16 + kc * 4);
                *(float4*)(As + node * 20 + kc * 4) = v;
            }
            // stage B tile (16 x 128)
            #pragma unroll
            for (int rep = 0; rep < 2; ++rep) {
                int fi = t + rep * 256;
                int r = fi >> 5, c = fi & 31;
                float4 v = *(const float4*)(B + (size_t)(kt * 16 + r) * 128 + c * 4);
                *(float4*)(Bs + r * 128 + c * 4) = v;
            }
            __syncthreads();
            #pragma unroll
            for (int kk0 = 0; kk0 < 16; kk0 += 4) {
                float4 b0 = *(const float4*)(Bs + (kk0 + 0) * 128 + tx * 4);
                float4 b1 = *(const float4*)(Bs + (kk0 + 1) * 128 + tx * 4);
                float4 b2 = *(const float4*)(Bs + (kk0 + 2) * 128 + tx * 4);
                float4 b3 = *(const float4*)(Bs + (kk0 + 3) * 128 + tx * 4);
                #pragma unroll
                for (int i = 0; i < 8; ++i) {
                    float4 a = *(const float4*)(As + (ty * 8 + i) * 20 + kk0);
                    acc[i][0] += a.x * b0.x; acc[i][1] += a.x * b0.y;
                    acc[i][2] += a.x * b0.z; acc[i][3] += a.x * b0.w;
                    acc[i][0] += a.y * b1.x; acc[i][1] += a.y * b1.y;
                    acc[i][2] += a.y * b1.z; acc[i][3] += a.y * b1.w;
                    acc[i][0] += a.z * b2.x; acc[i][1] += a.z * b2.y;
                    acc[i][2] += a.z * b2.z; acc[i][3] += a.z * b2.w;
                    acc[i][0] += a.w * b3.x; acc[i][1] += a.w * b3.y;
                    acc[i][2] += a.w * b3.z; acc[i][3] += a.w * b3.w;
                }
            }
            __syncthreads();
        }
    }

    // epilogue: bias + optional PReLU, coalesced float4 store
    float4 bv = *(const float4*)(bias + tx * 4);
    float4 av = make_float4(0.f, 0.f, 0.f, 0.f);
    if (prelu_a) av = *(const float4*)(prelu_a + tx * 4);
    #pragma unroll
    for (int i = 0; i < 8; ++i) {
        int m = m0 + ty * 8 + i;
        if (m >= M) continue;
        float4 o;
        o.x = acc[i][0] + bv.x;
        o.y = acc[i][1] + bv.y;
        o.z = acc[i][2] + bv.z;
        o.w = acc[i][3] + bv.w;
        if (prelu_a) {
            o.x = o.x >= 0.f ? o.x : av.x * o.x;
            o.y = o.y >= 0.f ? o.y : av.y * o.y;
            o.z = o.z >= 0.f ? o.z : av.z * o.z;
            o.w = o.w >= 0.f ? o.w : av.w * o.w;
        }
        *(float4*)(C + (size_t)m * 128 + tx * 4) = o;
    }
}

extern "C" void kernel_launch(void* const* d_in, const int* in_sizes, int n_in,
                              void* d_out, int out_size, void* d_ws, size_t ws_size,
                              hipStream_t stream) {
    const float* x      = (const float*)d_in[0];
    const int*   ei     = (const int*)d_in[1];
    const int*   et     = (const int*)d_in[2];
    const float* Wnum   = (const float*)d_in[3];
    const float* bnum   = (const float*)d_in[4];
    const float* Wcat   = (const float*)d_in[5];
    const float* bcat   = (const float*)d_in[6];
    const float* Win    = (const float*)d_in[7];
    const float* bin    = (const float*)d_in[8];
    const float* pa     = (const float*)d_in[9];
    const float* Wrel1  = (const float*)d_in[10];
    const float* Wroot1 = (const float*)d_in[11];
    const float* brg1   = (const float*)d_in[12];
    const float* Wrel2  = (const float*)d_in[13];
    const float* Wroot2 = (const float*)d_in[14];
    const float* brg2   = (const float*)d_in[15];
    const float* Wcls   = (const float*)d_in[16];
    const float* bcls   = (const float*)d_in[17];
    float* out = (float*)d_out;

    const int N = in_sizes[0] / 8;
    const int E = in_sizes[1] / 2;
    const int nseg = 2 * N;

    // workspace carve-up
    char* w = (char*)d_ws;
    float* hbuf = (float*)w;            w += (size_t)N * 128 * 4;      // 51.2 MB
    float* agg  = (float*)w;            w += (size_t)2 * N * 128 * 4;  // 102.4 MB (aliased h_pre)
    int* deg  = (int*)w;                w += (size_t)nseg * 4;
    int* cur  = (int*)w;                w += (size_t)nseg * 4;
    int* off  = (int*)w;                w += (size_t)nseg * 4;
    int* esrc = (int*)w;                w += (size_t)E * 4;
    int* bsum = (int*)w;                w += 1024 * 4;
    float* hpre = agg;  // pre-embed features alias the agg region

    hipMemsetAsync(deg, 0, (size_t)nseg * 2 * sizeof(int), stream); // deg + cur

    const int nb = (nseg + 255) / 256;
    const int gE = (E + 255) / 256;
    const int gm = (N + 63) / 64;

    k_pre<<<(N * 128 + 255) / 256, 256, 0, stream>>>(x, Wnum, bnum, Wcat, bcat, hpre, N);
    k_count<<<gE, 256, 0, stream>>>(ei, et, deg, E, N);
    k_scan1<<<nb, 256, 0, stream>>>(deg, off, bsum, nseg);
    k_scan2<<<1, 1024, 0, stream>>>(bsum, nb);
    k_scan3<<<nb, 256, 0, stream>>>(off, bsum, nseg);
    k_fill<<<gE, 256, 0, stream>>>(ei, et, off, cur, esrc, E, N);

    // embed: h0 = prelu(h_pre @ W_in + b_in)
    k_gemm<<<gm, 256, 0, stream>>>(hpre, Win, nullptr, nullptr, nullptr, nullptr,
                                   bin, pa, hbuf, N);
    // layer 1: out(d_out) = h0@W_root1 + mean0@Wrel1[0] + mean1@Wrel1[1] + b
    k_gather<<<nseg, 128, 0, stream>>>(hbuf, esrc, off, deg, agg);
    k_gemm<<<gm, 256, 0, stream>>>(hbuf, Wroot1,
                                   agg, Wrel1,
                                   agg + (size_t)N * 128, Wrel1 + 128 * 128,
                                   brg1, nullptr, out, N);
    // layer 2: hbuf = h1@W_root2 + ...
    k_gather<<<nseg, 128, 0, stream>>>(out, esrc, off, deg, agg);
    k_gemm<<<gm, 256, 0, stream>>>(out, Wroot2,
                                   agg, Wrel2,
                                   agg + (size_t)N * 128, Wrel2 + 128 * 128,
                                   brg2, nullptr, hbuf, N);
    // classifier
    k_gemm<<<gm, 256, 0, stream>>>(hbuf, Wcls, nullptr, nullptr, nullptr, nullptr,
                                   bcls, nullptr, out, N);
}

// Round 2
// 842.663 us; speedup vs baseline: 1.2449x; 1.2449x over previous
//
#include <hip/hip_runtime.h>
#include <cstdint>

// ---------------------------------------------------------------------------
// BotRGCN round 2: split-bf16 (hi+lo) MFMA GEMMs on the matrix pipe.
// All activations/weights stored as two bf16 planes (hi, lo): v ~= hi + lo
// with ~16-bit mantissa accuracy. GEMM computes Ah*Bh + Ah*Bl + Al*Bh.
// CSR gather-mean aggregation unchanged in structure, now on bf16 planes.
// ---------------------------------------------------------------------------

typedef short bf16x8 __attribute__((ext_vector_type(8)));
typedef float f32x4  __attribute__((ext_vector_type(4)));

__device__ __forceinline__ unsigned short f2bf(float f) {
    unsigned int u = __builtin_bit_cast(unsigned int, f);
    u += 0x7fff + ((u >> 16) & 1);          // RNE
    return (unsigned short)(u >> 16);
}
__device__ __forceinline__ float bf2f(unsigned short h) {
    unsigned int u = ((unsigned int)h) << 16;
    return __builtin_bit_cast(float, u);
}

__device__ __forceinline__ void gload_lds16(const void* g, void* l) {
    __builtin_amdgcn_global_load_lds(
        (const __attribute__((address_space(1))) void*)g,
        (__attribute__((address_space(3))) void*)l, 16, 0, 0);
}

// ---- feature pre-embed into hi/lo planes ----
__global__ __launch_bounds__(256) void k_pre(
    const float* __restrict__ x,
    const float* __restrict__ Wnum, const float* __restrict__ bnum,
    const float* __restrict__ Wcat, const float* __restrict__ bcat,
    unsigned short* __restrict__ hi, unsigned short* __restrict__ lo, int N)
{
    int gid = blockIdx.x * 256 + threadIdx.x;
    if (gid >= N * 128) return;
    int n = gid >> 7, k = gid & 127;
    const float* xr = x + n * 8;
    float acc;
    if (k < 64) {
        acc = bnum[k];
        #pragma unroll
        for (int p = 0; p < 5; ++p) acc += xr[p] * Wnum[p * 64 + k];
    } else {
        int kk = k - 64;
        acc = bcat[kk];
        #pragma unroll
        for (int p = 0; p < 3; ++p) acc += xr[5 + p] * Wcat[p * 64 + kk];
    }
    float v = acc >= 0.f ? acc : 0.01f * acc;
    unsigned short h = f2bf(v);
    hi[gid] = h;
    lo[gid] = f2bf(v - bf2f(h));
}

// ---- weight split+transpose: out[n][k] planes from W[k][n], 8 parts ----
struct WArgs {
    const float* W[8];
    unsigned short* hi[8];
    unsigned short* lo[8];
};
__global__ __launch_bounds__(256) void k_wsplit(WArgs a)
{
    int part = blockIdx.y;
    int idx = blockIdx.x * 256 + threadIdx.x;   // 16384 per part
    int n = idx >> 7, k = idx & 127;            // write coalesced in k
    float v = a.W[part][(size_t)k * 128 + n];
    unsigned short h = f2bf(v);
    a.hi[part][(size_t)n * 128 + k] = h;
    a.lo[part][(size_t)n * 128 + k] = f2bf(v - bf2f(h));
}

// ---- CSR build ----
__global__ __launch_bounds__(256) void k_count(
    const int* __restrict__ ei, const int* __restrict__ et,
    int* __restrict__ deg, int E, int N)
{
    int e = blockIdx.x * 256 + threadIdx.x;
    if (e >= E) return;
    int r = et[e], d = ei[E + e];
    atomicAdd(&deg[r * N + d], 1);
}

__global__ __launch_bounds__(256) void k_scan1(
    const int* __restrict__ deg, int* __restrict__ off,
    int* __restrict__ bsum, int n)
{
    __shared__ int s[256];
    int t = threadIdx.x;
    int i = blockIdx.x * 256 + t;
    int v = (i < n) ? deg[i] : 0;
    s[t] = v;
    __syncthreads();
    #pragma unroll
    for (int d = 1; d < 256; d <<= 1) {
        int add = (t >= d) ? s[t - d] : 0;
        __syncthreads();
        s[t] += add;
        __syncthreads();
    }
    if (i < n) off[i] = s[t] - v;
    if (t == 255) bsum[blockIdx.x] = s[255];
}

__global__ __launch_bounds__(1024) void k_scan2(int* __restrict__ bsum, int nb)
{
    __shared__ int s[1024];
    int t = threadIdx.x;
    int v = (t < nb) ? bsum[t] : 0;
    s[t] = v;
    __syncthreads();
    #pragma unroll
    for (int d = 1; d < 1024; d <<= 1) {
        int add = (t >= d) ? s[t - d] : 0;
        __syncthreads();
        s[t] += add;
        __syncthreads();
    }
    if (t < nb) bsum[t] = s[t] - v;
}

__global__ __launch_bounds__(256) void k_scan3(
    int* __restrict__ off, const int* __restrict__ bsum, int n)
{
    int i = blockIdx.x * 256 + threadIdx.x;
    if (i < n) off[i] += bsum[blockIdx.x];
}

__global__ __launch_bounds__(256) void k_fill(
    const int* __restrict__ ei, const int* __restrict__ et,
    const int* __restrict__ off, int* __restrict__ cur,
    int* __restrict__ esrc, int E, int N)
{
    int e = blockIdx.x * 256 + threadIdx.x;
    if (e >= E) return;
    int r = et[e], d = ei[E + e], s = ei[e];
    int i = r * N + d;
    int pos = off[i] + atomicAdd(&cur[i], 1);
    esrc[pos] = s;
}

// ---- mean aggregation on hi/lo planes ----
__global__ __launch_bounds__(128) void k_gather(
    const unsigned short* __restrict__ h_hi, const unsigned short* __restrict__ h_lo,
    const int* __restrict__ esrc,
    const int* __restrict__ off, const int* __restrict__ deg,
    unsigned short* __restrict__ a_hi, unsigned short* __restrict__ a_lo)
{
    int i = blockIdx.x;
    int f = threadIdx.x;
    int cnt = deg[i], st = off[i];
    float s0 = 0.f, s1 = 0.f, s2 = 0.f, s3 = 0.f;
    int e = 0;
    for (; e + 4 <= cnt; e += 4) {
        int i0 = esrc[st + e + 0];
        int i1 = esrc[st + e + 1];
        int i2 = esrc[st + e + 2];
        int i3 = esrc[st + e + 3];
        s0 += bf2f(h_hi[(size_t)i0 * 128 + f]) + bf2f(h_lo[(size_t)i0 * 128 + f]);
        s1 += bf2f(h_hi[(size_t)i1 * 128 + f]) + bf2f(h_lo[(size_t)i1 * 128 + f]);
        s2 += bf2f(h_hi[(size_t)i2 * 128 + f]) + bf2f(h_lo[(size_t)i2 * 128 + f]);
        s3 += bf2f(h_hi[(size_t)i3 * 128 + f]) + bf2f(h_lo[(size_t)i3 * 128 + f]);
    }
    for (; e < cnt; ++e) {
        int i0 = esrc[st + e];
        s0 += bf2f(h_hi[(size_t)i0 * 128 + f]) + bf2f(h_lo[(size_t)i0 * 128 + f]);
    }
    float s = (s0 + s1) + (s2 + s3);
    float m = s / (float)(cnt > 1 ? cnt : 1);
    unsigned short h = f2bf(m);
    a_hi[(size_t)i * 128 + f] = h;
    a_lo[(size_t)i * 128 + f] = f2bf(m - bf2f(h));
}

// ---- split-bf16 MFMA GEMM ----
// C[M,128] = act( sum_p (A_p approx) @ (B_p approx) + bias )
// A planes: [M][128] bf16 hi/lo.  B planes pre-transposed: Bt[n][k] bf16 hi/lo.
// Block tile 128x128, 4 waves in 2x2 grid of 64x64 wave tiles. BK=32.
// LDS is frag-major: 32 blocks of 1 KB; block = one 16-row MFMA fragment set
// in lane order (lane l's 16 B at l*16) -> conflict-free ds_read_b128 and
// global_load_lds-compatible staging.
struct GArgs {
    const unsigned short* A_hi[3];
    const unsigned short* A_lo[3];
    const unsigned short* B_hi[3];   // transposed [n][k]
    const unsigned short* B_lo[3];
    const float* bias;
    const float* prelu;              // nullable
    float* Cf;                       // if non-null: fp32 output
    unsigned short* C_hi;            // else hi/lo plane output
    unsigned short* C_lo;
    int M;
    int P;
};

__global__ __launch_bounds__(256) void k_mgemm(GArgs g)
{
    __shared__ unsigned short lds[32 * 512];   // 32 KB
    const int t = threadIdx.x;
    const int w = t >> 6, lane = t & 63;
    const int laneL = lane & 15, laneH = lane >> 4;
    const int wi = w >> 1, wj = w & 1;
    const int m0 = blockIdx.x * 128;
    const int Mm1 = g.M - 1;

    f32x4 acc[4][4];
    #pragma unroll
    for (int a = 0; a < 4; ++a)
        #pragma unroll
        for (int b = 0; b < 4; ++b)
            acc[a][b] = (f32x4){0.f, 0.f, 0.f, 0.f};

    for (int p = 0; p < g.P; ++p) {
        const unsigned short* plane;
        if      (w == 0) plane = g.A_hi[p];
        else if (w == 1) plane = g.A_lo[p];
        else if (w == 2) plane = g.B_hi[p];
        else             plane = g.B_lo[p];
        const bool isA = (w < 2);

        for (int kt = 0; kt < 4; ++kt) {
            // stage: wave w stages its tile as 8 frag-blocks of 1 KB
            #pragma unroll
            for (int j = 0; j < 8; ++j) {
                int rc = j * 16 + laneL;
                int row = isA ? (m0 + rc <= Mm1 ? m0 + rc : Mm1) : rc;
                const unsigned short* gp = plane + (size_t)row * 128 + kt * 32 + laneH * 8;
                unsigned short* lp = &lds[(w * 8 + j) * 512];  // wave-uniform base
                gload_lds16(gp, lp);
            }
            __syncthreads();

            const bf16x8* fr = (const bf16x8*)lds;  // 64 frags of 16B per block
            bf16x8 ah[4], al[4], bh[4], bl[4];
            #pragma unroll
            for (int mi = 0; mi < 4; ++mi) {
                ah[mi] = fr[(0  + wi * 4 + mi) * 64 + lane];
                al[mi] = fr[(8  + wi * 4 + mi) * 64 + lane];
            }
            #pragma unroll
            for (int nj = 0; nj < 4; ++nj) {
                bh[nj] = fr[(16 + wj * 4 + nj) * 64 + lane];
                bl[nj] = fr[(24 + wj * 4 + nj) * 64 + lane];
            }
            #pragma unroll
            for (int mi = 0; mi < 4; ++mi)
                #pragma unroll
                for (int nj = 0; nj < 4; ++nj) {
                    acc[mi][nj] = __builtin_amdgcn_mfma_f32_16x16x32_bf16(
                        ah[mi], bh[nj], acc[mi][nj], 0, 0, 0);
                    acc[mi][nj] = __builtin_amdgcn_mfma_f32_16x16x32_bf16(
                        ah[mi], bl[nj], acc[mi][nj], 0, 0, 0);
                    acc[mi][nj] = __builtin_amdgcn_mfma_f32_16x16x32_bf16(
                        al[mi], bh[nj], acc[mi][nj], 0, 0, 0);
                }
            __syncthreads();
        }
    }

    // epilogue: C/D layout col=lane&15, row=(lane>>4)*4+reg
    const bool hasPrelu = (g.prelu != nullptr);
    const bool outF32 = (g.Cf != nullptr);
    #pragma unroll
    for (int nj = 0; nj < 4; ++nj) {
        int col = wj * 64 + nj * 16 + laneL;
        float bv = g.bias[col];
        float av = hasPrelu ? g.prelu[col] : 0.f;
        #pragma unroll
        for (int mi = 0; mi < 4; ++mi) {
            #pragma unroll
            for (int r = 0; r < 4; ++r) {
                int m = m0 + wi * 64 + mi * 16 + laneH * 4 + r;
                if (m >= g.M) continue;
                float v = acc[mi][nj][r] + bv;
                if (hasPrelu) v = v >= 0.f ? v : av * v;
                size_t idx = (size_t)m * 128 + col;
                if (outF32) {
                    g.Cf[idx] = v;
                } else {
                    unsigned short h = f2bf(v);
                    g.C_hi[idx] = h;
                    g.C_lo[idx] = f2bf(v - bf2f(h));
                }
            }
        }
    }
}

extern "C" void kernel_launch(void* const* d_in, const int* in_sizes, int n_in,
                              void* d_out, int out_size, void* d_ws, size_t ws_size,
                              hipStream_t stream) {
    const float* x      = (const float*)d_in[0];
    const int*   ei     = (const int*)d_in[1];
    const int*   et     = (const int*)d_in[2];
    const float* Wnum   = (const float*)d_in[3];
    const float* bnum   = (const float*)d_in[4];
    const float* Wcat   = (const float*)d_in[5];
    const float* bcat   = (const float*)d_in[6];
    const float* Win    = (const float*)d_in[7];
    const float* bin    = (const float*)d_in[8];
    const float* pa     = (const float*)d_in[9];
    const float* Wrel1  = (const float*)d_in[10];
    const float* Wroot1 = (const float*)d_in[11];
    const float* brg1   = (const float*)d_in[12];
    const float* Wrel2  = (const float*)d_in[13];
    const float* Wroot2 = (const float*)d_in[14];
    const float* brg2   = (const float*)d_in[15];
    const float* Wcls   = (const float*)d_in[16];
    const float* bcls   = (const float*)d_in[17];
    float* out = (float*)d_out;

    const int N = in_sizes[0] / 8;
    const int E = in_sizes[1] / 2;
    const int nseg = 2 * N;
    const size_t NH = (size_t)N * 128;

    // ---- workspace carve-up (all 256B-aligned) ----
    char* w = (char*)d_ws;
    unsigned short* h0_hi = (unsigned short*)w;  w += NH * 2;          // 25.6 MB
    unsigned short* h0_lo = (unsigned short*)w;  w += NH * 2;          // 25.6 MB
    unsigned short* agg_hi = (unsigned short*)w; w += 2 * NH * 2;      // 51.2 MB
    unsigned short* agg_lo = (unsigned short*)w; w += 2 * NH * 2;      // 51.2 MB
    int* deg  = (int*)w;  w += (size_t)nseg * 4;
    int* cur  = (int*)w;  w += (size_t)nseg * 4;
    int* off  = (int*)w;  w += (size_t)nseg * 4;
    int* esrc = (int*)w;  w += (size_t)E * 4;
    int* bsum = (int*)w;  w += 1024 * 4;
    unsigned short* wplanes = (unsigned short*)w;  w += 8 * 2 * 16384 * 2; // 512 KB

    // hpre planes alias agg region (dead before gather1 writes agg)
    unsigned short* hp_hi = agg_hi;
    unsigned short* hp_lo = agg_hi + NH;
    // h1 planes live in d_out (dead before cls gemm overwrites d_out)
    unsigned short* h1_hi = (unsigned short*)d_out;
    unsigned short* h1_lo = h1_hi + NH;
    // h2 reuses h0 buffers (h0 dead after layer-1 gemm)
    unsigned short* h2_hi = h0_hi;
    unsigned short* h2_lo = h0_lo;

    // weight plane pointers: parts 0..7 = Win, Wroot1, Wrel1[0], Wrel1[1],
    //                                      Wroot2, Wrel2[0], Wrel2[1], Wcls
    unsigned short* whi[8];
    unsigned short* wlo[8];
    for (int i = 0; i < 8; ++i) {
        whi[i] = wplanes + (size_t)i * 2 * 16384;
        wlo[i] = whi[i] + 16384;
    }

    hipMemsetAsync(deg, 0, (size_t)nseg * 2 * sizeof(int), stream); // deg + cur

    // weight split+transpose
    {
        WArgs a;
        a.W[0] = Win;   a.W[1] = Wroot1; a.W[2] = Wrel1; a.W[3] = Wrel1 + 16384;
        a.W[4] = Wroot2; a.W[5] = Wrel2; a.W[6] = Wrel2 + 16384; a.W[7] = Wcls;
        for (int i = 0; i < 8; ++i) { a.hi[i] = whi[i]; a.lo[i] = wlo[i]; }
        k_wsplit<<<dim3(64, 8), 256, 0, stream>>>(a);
    }

    const int nb = (nseg + 255) / 256;
    const int gE = (E + 255) / 256;
    const int gm = (N + 127) / 128;

    k_pre<<<(N * 128 + 255) / 256, 256, 0, stream>>>(x, Wnum, bnum, Wcat, bcat, hp_hi, hp_lo, N);
    k_count<<<gE, 256, 0, stream>>>(ei, et, deg, E, N);
    k_scan1<<<nb, 256, 0, stream>>>(deg, off, bsum, nseg);
    k_scan2<<<1, 1024, 0, stream>>>(bsum, nb);
    k_scan3<<<nb, 256, 0, stream>>>(off, bsum, nseg);
    k_fill<<<gE, 256, 0, stream>>>(ei, et, off, cur, esrc, E, N);

    // embed: h0 = prelu(hpre @ W_in + b_in)
    {
        GArgs g = {};
        g.A_hi[0] = hp_hi; g.A_lo[0] = hp_lo;
        g.B_hi[0] = whi[0]; g.B_lo[0] = wlo[0];
        g.bias = bin; g.prelu = pa;
        g.Cf = nullptr; g.C_hi = h0_hi; g.C_lo = h0_lo;
        g.M = N; g.P = 1;
        k_mgemm<<<gm, 256, 0, stream>>>(g);
    }
    // layer 1
    k_gather<<<nseg, 128, 0, stream>>>(h0_hi, h0_lo, esrc, off, deg, agg_hi, agg_lo);
    {
        GArgs g = {};
        g.A_hi[0] = h0_hi;       g.A_lo[0] = h0_lo;
        g.A_hi[1] = agg_hi;      g.A_lo[1] = agg_lo;
        g.A_hi[2] = agg_hi + NH; g.A_lo[2] = agg_lo + NH;
        g.B_hi[0] = whi[1]; g.B_lo[0] = wlo[1];
        g.B_hi[1] = whi[2]; g.B_lo[1] = wlo[2];
        g.B_hi[2] = whi[3]; g.B_lo[2] = wlo[3];
        g.bias = brg1; g.prelu = nullptr;
        g.Cf = nullptr; g.C_hi = h1_hi; g.C_lo = h1_lo;
        g.M = N; g.P = 3;
        k_mgemm<<<gm, 256, 0, stream>>>(g);
    }
    // layer 2
    k_gather<<<nseg, 128, 0, stream>>>(h1_hi, h1_lo, esrc, off, deg, agg_hi, agg_lo);
    {
        GArgs g = {};
        g.A_hi[0] = h1_hi;       g.A_lo[0] = h1_lo;
        g.A_hi[1] = agg_hi;      g.A_lo[1] = agg_lo;
        g.A_hi[2] = agg_hi + NH; g.A_lo[2] = agg_lo + NH;
        g.B_hi[0] = whi[4]; g.B_lo[0] = wlo[4];
        g.B_hi[1] = whi[5]; g.B_lo[1] = wlo[5];
        g.B_hi[2] = whi[6]; g.B_lo[2] = wlo[6];
        g.bias = brg2; g.prelu = nullptr;
        g.Cf = nullptr; g.C_hi = h2_hi; g.C_lo = h2_lo;
        g.M = N; g.P = 3;
        k_mgemm<<<gm, 256, 0, stream>>>(g);
    }
    // classifier -> fp32 out
    {
        GArgs g = {};
        g.A_hi[0] = h2_hi; g.A_lo[0] = h2_lo;
        g.B_hi[0] = whi[7]; g.B_lo[0] = wlo[7];
        g.bias = bcls; g.prelu = nullptr;
        g.Cf = out; g.C_hi = nullptr; g.C_lo = nullptr;
        g.M = N; g.P = 1;
        k_mgemm<<<gm, 256, 0, stream>>>(g);
    }
}

// Round 3
// 700.512 us; speedup vs baseline: 1.4975x; 1.2029x over previous
//
#include <hip/hip_runtime.h>
#include <cstdint>

// ---------------------------------------------------------------------------
// BotRGCN round 3: split-bf16 MFMA GEMMs + bf16-only gather.
// - Activations stored as bf16 hi/lo planes; GEMM computes Ah*Bh+Ah*Bl(+Al*Bh).
// - Gather-mean aggregation reads ONLY the hi plane (error budget analysis:
//   adds ~<1e-4 vs 9.7e-4 threshold), one wave per (rel,dst) segment,
//   uint32-packed 2-feature loads -> 256 B per wave-instruction.
// - agg is bf16 hi-only; GEMM skips the Al*Bh term for those parts.
// ---------------------------------------------------------------------------

typedef short bf16x8 __attribute__((ext_vector_type(8)));
typedef float f32x4  __attribute__((ext_vector_type(4)));

__device__ __forceinline__ unsigned short f2bf(float f) {
    unsigned int u = __builtin_bit_cast(unsigned int, f);
    u += 0x7fff + ((u >> 16) & 1);          // RNE
    return (unsigned short)(u >> 16);
}
__device__ __forceinline__ float bf2f(unsigned short h) {
    unsigned int u = ((unsigned int)h) << 16;
    return __builtin_bit_cast(float, u);
}
__device__ __forceinline__ float lo16f(unsigned int u) {   // low ushort as bf16
    return __builtin_bit_cast(float, u << 16);
}
__device__ __forceinline__ float hi16f(unsigned int u) {   // high ushort as bf16
    return __builtin_bit_cast(float, u & 0xffff0000u);
}

__device__ __forceinline__ void gload_lds16(const void* g, void* l) {
    __builtin_amdgcn_global_load_lds(
        (const __attribute__((address_space(1))) void*)g,
        (__attribute__((address_space(3))) void*)l, 16, 0, 0);
}

// ---- feature pre-embed into hi/lo planes ----
__global__ __launch_bounds__(256) void k_pre(
    const float* __restrict__ x,
    const float* __restrict__ Wnum, const float* __restrict__ bnum,
    const float* __restrict__ Wcat, const float* __restrict__ bcat,
    unsigned short* __restrict__ hi, unsigned short* __restrict__ lo, int N)
{
    int gid = blockIdx.x * 256 + threadIdx.x;
    if (gid >= N * 128) return;
    int n = gid >> 7, k = gid & 127;
    const float* xr = x + n * 8;
    float acc;
    if (k < 64) {
        acc = bnum[k];
        #pragma unroll
        for (int p = 0; p < 5; ++p) acc += xr[p] * Wnum[p * 64 + k];
    } else {
        int kk = k - 64;
        acc = bcat[kk];
        #pragma unroll
        for (int p = 0; p < 3; ++p) acc += xr[5 + p] * Wcat[p * 64 + kk];
    }
    float v = acc >= 0.f ? acc : 0.01f * acc;
    unsigned short h = f2bf(v);
    hi[gid] = h;
    lo[gid] = f2bf(v - bf2f(h));
}

// ---- weight split+transpose: out[n][k] planes from W[k][n], 8 parts ----
struct WArgs {
    const float* W[8];
    unsigned short* hi[8];
    unsigned short* lo[8];
};
__global__ __launch_bounds__(256) void k_wsplit(WArgs a)
{
    int part = blockIdx.y;
    int idx = blockIdx.x * 256 + threadIdx.x;   // 16384 per part
    int n = idx >> 7, k = idx & 127;            // write coalesced in k
    float v = a.W[part][(size_t)k * 128 + n];
    unsigned short h = f2bf(v);
    a.hi[part][(size_t)n * 128 + k] = h;
    a.lo[part][(size_t)n * 128 + k] = f2bf(v - bf2f(h));
}

// ---- CSR build ----
__global__ __launch_bounds__(256) void k_count(
    const int* __restrict__ ei, const int* __restrict__ et,
    int* __restrict__ deg, int E, int N)
{
    int e = blockIdx.x * 256 + threadIdx.x;
    if (e >= E) return;
    int r = et[e], d = ei[E + e];
    atomicAdd(&deg[r * N + d], 1);
}

__global__ __launch_bounds__(256) void k_scan1(
    const int* __restrict__ deg, int* __restrict__ off,
    int* __restrict__ bsum, int n)
{
    __shared__ int s[256];
    int t = threadIdx.x;
    int i = blockIdx.x * 256 + t;
    int v = (i < n) ? deg[i] : 0;
    s[t] = v;
    __syncthreads();
    #pragma unroll
    for (int d = 1; d < 256; d <<= 1) {
        int add = (t >= d) ? s[t - d] : 0;
        __syncthreads();
        s[t] += add;
        __syncthreads();
    }
    if (i < n) off[i] = s[t] - v;
    if (t == 255) bsum[blockIdx.x] = s[255];
}

__global__ __launch_bounds__(1024) void k_scan2(int* __restrict__ bsum, int nb)
{
    __shared__ int s[1024];
    int t = threadIdx.x;
    int v = (t < nb) ? bsum[t] : 0;
    s[t] = v;
    __syncthreads();
    #pragma unroll
    for (int d = 1; d < 1024; d <<= 1) {
        int add = (t >= d) ? s[t - d] : 0;
        __syncthreads();
        s[t] += add;
        __syncthreads();
    }
    if (t < nb) bsum[t] = s[t] - v;
}

__global__ __launch_bounds__(256) void k_scan3(
    int* __restrict__ off, const int* __restrict__ bsum, int n)
{
    int i = blockIdx.x * 256 + threadIdx.x;
    if (i < n) off[i] += bsum[blockIdx.x];
}

__global__ __launch_bounds__(256) void k_fill(
    const int* __restrict__ ei, const int* __restrict__ et,
    const int* __restrict__ off, int* __restrict__ cur,
    int* __restrict__ esrc, int E, int N)
{
    int e = blockIdx.x * 256 + threadIdx.x;
    if (e >= E) return;
    int r = et[e], d = ei[E + e], s = ei[e];
    int i = r * N + d;
    int pos = off[i] + atomicAdd(&cur[i], 1);
    esrc[pos] = s;
}

// ---- mean aggregation, bf16 hi plane only ----
// One wave per (rel,dst) segment; lane handles 2 packed features (uint32).
// 4 blocks' worth of segments per 256-thread block.
__global__ __launch_bounds__(256) void k_gather(
    const unsigned short* __restrict__ h_hi,
    const int* __restrict__ esrc,
    const int* __restrict__ off, const int* __restrict__ deg,
    unsigned short* __restrict__ a_hi, int nseg)
{
    int i = blockIdx.x * 4 + (threadIdx.x >> 6);
    if (i >= nseg) return;
    int lane = threadIdx.x & 63;
    int cnt = deg[i], st = off[i];
    const unsigned int* hp = (const unsigned int*)h_hi;   // [row][64] packed
    float sa0 = 0.f, sb0 = 0.f, sa1 = 0.f, sb1 = 0.f;
    float sa2 = 0.f, sb2 = 0.f, sa3 = 0.f, sb3 = 0.f;
    int e = 0;
    for (; e + 4 <= cnt; e += 4) {
        int i0 = esrc[st + e + 0];
        int i1 = esrc[st + e + 1];
        int i2 = esrc[st + e + 2];
        int i3 = esrc[st + e + 3];
        unsigned int u0 = hp[(size_t)i0 * 64 + lane];
        unsigned int u1 = hp[(size_t)i1 * 64 + lane];
        unsigned int u2 = hp[(size_t)i2 * 64 + lane];
        unsigned int u3 = hp[(size_t)i3 * 64 + lane];
        sa0 += lo16f(u0); sb0 += hi16f(u0);
        sa1 += lo16f(u1); sb1 += hi16f(u1);
        sa2 += lo16f(u2); sb2 += hi16f(u2);
        sa3 += lo16f(u3); sb3 += hi16f(u3);
    }
    for (; e < cnt; ++e) {
        unsigned int u = hp[(size_t)esrc[st + e] * 64 + lane];
        sa0 += lo16f(u); sb0 += hi16f(u);
    }
    float inv = 1.0f / (float)(cnt > 1 ? cnt : 1);
    float ma = ((sa0 + sa1) + (sa2 + sa3)) * inv;   // feature 2*lane
    float mb = ((sb0 + sb1) + (sb2 + sb3)) * inv;   // feature 2*lane+1
    unsigned int outp = (unsigned int)f2bf(ma) | ((unsigned int)f2bf(mb) << 16);
    ((unsigned int*)a_hi)[(size_t)i * 64 + lane] = outp;
}

// ---- split-bf16 MFMA GEMM ----
// C[M,128] = act( sum_p (A_p approx) @ (B_p approx) + bias )
// Per part: Ah*Bh + Ah*Bl (+ Al*Bh if alo[p]).
// Block tile 128x128, 4 waves (2x2 of 64x64), BK=32, frag-major LDS.
struct GArgs {
    const unsigned short* A_hi[3];
    const unsigned short* A_lo[3];
    const unsigned short* B_hi[3];   // transposed [n][k]
    const unsigned short* B_lo[3];
    int alo[3];                      // 1 if A_lo[p] exists
    const float* bias;
    const float* prelu;              // nullable
    float* Cf;                       // if non-null: fp32 output
    unsigned short* C_hi;            // else hi/lo plane output
    unsigned short* C_lo;
    int M;
    int P;
};

__global__ __launch_bounds__(256) void k_mgemm(GArgs g)
{
    __shared__ unsigned short lds[32 * 512];   // 32 KB
    const int t = threadIdx.x;
    const int w = t >> 6, lane = t & 63;
    const int laneL = lane & 15, laneH = lane >> 4;
    const int wi = w >> 1, wj = w & 1;
    const int m0 = blockIdx.x * 128;
    const int Mm1 = g.M - 1;

    f32x4 acc[4][4];
    #pragma unroll
    for (int a = 0; a < 4; ++a)
        #pragma unroll
        for (int b = 0; b < 4; ++b)
            acc[a][b] = (f32x4){0.f, 0.f, 0.f, 0.f};

    for (int p = 0; p < g.P; ++p) {
        const bool hasAlo = g.alo[p] != 0;
        const unsigned short* plane;
        if      (w == 0) plane = g.A_hi[p];
        else if (w == 1) plane = hasAlo ? g.A_lo[p] : nullptr;
        else if (w == 2) plane = g.B_hi[p];
        else             plane = g.B_lo[p];
        const bool isA = (w < 2);

        for (int kt = 0; kt < 4; ++kt) {
            if (plane) {
                #pragma unroll
                for (int j = 0; j < 8; ++j) {
                    int rc = j * 16 + laneL;
                    int row = isA ? (m0 + rc <= Mm1 ? m0 + rc : Mm1) : rc;
                    const unsigned short* gp = plane + (size_t)row * 128 + kt * 32 + laneH * 8;
                    unsigned short* lp = &lds[(w * 8 + j) * 512];  // wave-uniform base
                    gload_lds16(gp, lp);
                }
            }
            __syncthreads();

            const bf16x8* fr = (const bf16x8*)lds;  // 64 frags of 16B per block
            bf16x8 ah[4], al[4], bh[4], bl[4];
            #pragma unroll
            for (int mi = 0; mi < 4; ++mi)
                ah[mi] = fr[(0 + wi * 4 + mi) * 64 + lane];
            if (hasAlo) {
                #pragma unroll
                for (int mi = 0; mi < 4; ++mi)
                    al[mi] = fr[(8 + wi * 4 + mi) * 64 + lane];
            }
            #pragma unroll
            for (int nj = 0; nj < 4; ++nj) {
                bh[nj] = fr[(16 + wj * 4 + nj) * 64 + lane];
                bl[nj] = fr[(24 + wj * 4 + nj) * 64 + lane];
            }
            #pragma unroll
            for (int mi = 0; mi < 4; ++mi)
                #pragma unroll
                for (int nj = 0; nj < 4; ++nj) {
                    acc[mi][nj] = __builtin_amdgcn_mfma_f32_16x16x32_bf16(
                        ah[mi], bh[nj], acc[mi][nj], 0, 0, 0);
                    acc[mi][nj] = __builtin_amdgcn_mfma_f32_16x16x32_bf16(
                        ah[mi], bl[nj], acc[mi][nj], 0, 0, 0);
                    if (hasAlo)
                        acc[mi][nj] = __builtin_amdgcn_mfma_f32_16x16x32_bf16(
                            al[mi], bh[nj], acc[mi][nj], 0, 0, 0);
                }
            __syncthreads();
        }
    }

    // epilogue: C/D layout col=lane&15, row=(lane>>4)*4+reg
    const bool hasPrelu = (g.prelu != nullptr);
    const bool outF32 = (g.Cf != nullptr);
    #pragma unroll
    for (int nj = 0; nj < 4; ++nj) {
        int col = wj * 64 + nj * 16 + laneL;
        float bv = g.bias[col];
        float av = hasPrelu ? g.prelu[col] : 0.f;
        #pragma unroll
        for (int mi = 0; mi < 4; ++mi) {
            #pragma unroll
            for (int r = 0; r < 4; ++r) {
                int m = m0 + wi * 64 + mi * 16 + laneH * 4 + r;
                if (m >= g.M) continue;
                float v = acc[mi][nj][r] + bv;
                if (hasPrelu) v = v >= 0.f ? v : av * v;
                size_t idx = (size_t)m * 128 + col;
                if (outF32) {
                    g.Cf[idx] = v;
                } else {
                    unsigned short h = f2bf(v);
                    g.C_hi[idx] = h;
                    g.C_lo[idx] = f2bf(v - bf2f(h));
                }
            }
        }
    }
}

extern "C" void kernel_launch(void* const* d_in, const int* in_sizes, int n_in,
                              void* d_out, int out_size, void* d_ws, size_t ws_size,
                              hipStream_t stream) {
    const float* x      = (const float*)d_in[0];
    const int*   ei     = (const int*)d_in[1];
    const int*   et     = (const int*)d_in[2];
    const float* Wnum   = (const float*)d_in[3];
    const float* bnum   = (const float*)d_in[4];
    const float* Wcat   = (const float*)d_in[5];
    const float* bcat   = (const float*)d_in[6];
    const float* Win    = (const float*)d_in[7];
    const float* bin    = (const float*)d_in[8];
    const float* pa     = (const float*)d_in[9];
    const float* Wrel1  = (const float*)d_in[10];
    const float* Wroot1 = (const float*)d_in[11];
    const float* brg1   = (const float*)d_in[12];
    const float* Wrel2  = (const float*)d_in[13];
    const float* Wroot2 = (const float*)d_in[14];
    const float* brg2   = (const float*)d_in[15];
    const float* Wcls   = (const float*)d_in[16];
    const float* bcls   = (const float*)d_in[17];
    float* out = (float*)d_out;

    const int N = in_sizes[0] / 8;
    const int E = in_sizes[1] / 2;
    const int nseg = 2 * N;
    const size_t NH = (size_t)N * 128;

    // ---- workspace carve-up ----
    char* w = (char*)d_ws;
    unsigned short* h0_hi = (unsigned short*)w;  w += NH * 2;          // 25.6 MB
    unsigned short* h0_lo = (unsigned short*)w;  w += NH * 2;          // 25.6 MB
    unsigned short* agg_hi = (unsigned short*)w; w += 2 * NH * 2;      // 51.2 MB
    int* deg  = (int*)w;  w += (size_t)nseg * 4;
    int* cur  = (int*)w;  w += (size_t)nseg * 4;
    int* off  = (int*)w;  w += (size_t)nseg * 4;
    int* esrc = (int*)w;  w += (size_t)E * 4;
    int* bsum = (int*)w;  w += 1024 * 4;
    unsigned short* wplanes = (unsigned short*)w;  w += 8 * 2 * 16384 * 2; // 512 KB

    // hpre planes alias agg region (dead before gather1 writes agg)
    unsigned short* hp_hi = agg_hi;
    unsigned short* hp_lo = agg_hi + NH;
    // h1 planes live in d_out (dead before cls gemm overwrites d_out)
    unsigned short* h1_hi = (unsigned short*)d_out;
    unsigned short* h1_lo = h1_hi + NH;
    // h2 reuses h0 buffers (h0 dead after layer-1 gemm)
    unsigned short* h2_hi = h0_hi;
    unsigned short* h2_lo = h0_lo;

    unsigned short* whi[8];
    unsigned short* wlo[8];
    for (int i = 0; i < 8; ++i) {
        whi[i] = wplanes + (size_t)i * 2 * 16384;
        wlo[i] = whi[i] + 16384;
    }

    hipMemsetAsync(deg, 0, (size_t)nseg * 2 * sizeof(int), stream); // deg + cur

    {
        WArgs a;
        a.W[0] = Win;   a.W[1] = Wroot1; a.W[2] = Wrel1; a.W[3] = Wrel1 + 16384;
        a.W[4] = Wroot2; a.W[5] = Wrel2; a.W[6] = Wrel2 + 16384; a.W[7] = Wcls;
        for (int i = 0; i < 8; ++i) { a.hi[i] = whi[i]; a.lo[i] = wlo[i]; }
        k_wsplit<<<dim3(64, 8), 256, 0, stream>>>(a);
    }

    const int nb = (nseg + 255) / 256;
    const int gE = (E + 255) / 256;
    const int gm = (N + 127) / 128;
    const int gg = (nseg + 3) / 4;

    k_pre<<<(N * 128 + 255) / 256, 256, 0, stream>>>(x, Wnum, bnum, Wcat, bcat, hp_hi, hp_lo, N);
    k_count<<<gE, 256, 0, stream>>>(ei, et, deg, E, N);
    k_scan1<<<nb, 256, 0, stream>>>(deg, off, bsum, nseg);
    k_scan2<<<1, 1024, 0, stream>>>(bsum, nb);
    k_scan3<<<nb, 256, 0, stream>>>(off, bsum, nseg);
    k_fill<<<gE, 256, 0, stream>>>(ei, et, off, cur, esrc, E, N);

    // embed: h0 = prelu(hpre @ W_in + b_in)
    {
        GArgs g = {};
        g.A_hi[0] = hp_hi; g.A_lo[0] = hp_lo; g.alo[0] = 1;
        g.B_hi[0] = whi[0]; g.B_lo[0] = wlo[0];
        g.bias = bin; g.prelu = pa;
        g.Cf = nullptr; g.C_hi = h0_hi; g.C_lo = h0_lo;
        g.M = N; g.P = 1;
        k_mgemm<<<gm, 256, 0, stream>>>(g);
    }
    // layer 1
    k_gather<<<gg, 256, 0, stream>>>(h0_hi, esrc, off, deg, agg_hi, nseg);
    {
        GArgs g = {};
        g.A_hi[0] = h0_hi;       g.A_lo[0] = h0_lo;  g.alo[0] = 1;
        g.A_hi[1] = agg_hi;      g.alo[1] = 0;
        g.A_hi[2] = agg_hi + NH; g.alo[2] = 0;
        g.B_hi[0] = whi[1]; g.B_lo[0] = wlo[1];
        g.B_hi[1] = whi[2]; g.B_lo[1] = wlo[2];
        g.B_hi[2] = whi[3]; g.B_lo[2] = wlo[3];
        g.bias = brg1; g.prelu = nullptr;
        g.Cf = nullptr; g.C_hi = h1_hi; g.C_lo = h1_lo;
        g.M = N; g.P = 3;
        k_mgemm<<<gm, 256, 0, stream>>>(g);
    }
    // layer 2
    k_gather<<<gg, 256, 0, stream>>>(h1_hi, esrc, off, deg, agg_hi, nseg);
    {
        GArgs g = {};
        g.A_hi[0] = h1_hi;       g.A_lo[0] = h1_lo;  g.alo[0] = 1;
        g.A_hi[1] = agg_hi;      g.alo[1] = 0;
        g.A_hi[2] = agg_hi + NH; g.alo[2] = 0;
        g.B_hi[0] = whi[4]; g.B_lo[0] = wlo[4];
        g.B_hi[1] = whi[5]; g.B_lo[1] = wlo[5];
        g.B_hi[2] = whi[6]; g.B_lo[2] = wlo[6];
        g.bias = brg2; g.prelu = nullptr;
        g.Cf = nullptr; g.C_hi = h2_hi; g.C_lo = h2_lo;
        g.M = N; g.P = 3;
        k_mgemm<<<gm, 256, 0, stream>>>(g);
    }
    // classifier -> fp32 out
    {
        GArgs g = {};
        g.A_hi[0] = h2_hi; g.A_lo[0] = h2_lo; g.alo[0] = 1;
        g.B_hi[0] = whi[7]; g.B_lo[0] = wlo[7];
        g.bias = bcls; g.prelu = nullptr;
        g.Cf = out; g.C_hi = nullptr; g.C_lo = nullptr;
        g.M = N; g.P = 1;
        k_mgemm<<<gm, 256, 0, stream>>>(g);
    }
}

// Round 4
// 665.261 us; speedup vs baseline: 1.5768x; 1.0530x over previous
//
#include <hip/hip_runtime.h>
#include <cstdint>

// ---------------------------------------------------------------------------
// BotRGCN round 4: split-bf16 MFMA GEMMs + bf16 gather + fast CSR build.
// CSR build: k_rank (atomicAdd-with-return -> deg + coalesced rank write),
// scan, k_scatter (atomic-free, 4 edges/thread batched scatter).
// ---------------------------------------------------------------------------

typedef short bf16x8 __attribute__((ext_vector_type(8)));
typedef float f32x4  __attribute__((ext_vector_type(4)));

__device__ __forceinline__ unsigned short f2bf(float f) {
    unsigned int u = __builtin_bit_cast(unsigned int, f);
    u += 0x7fff + ((u >> 16) & 1);          // RNE
    return (unsigned short)(u >> 16);
}
__device__ __forceinline__ float bf2f(unsigned short h) {
    unsigned int u = ((unsigned int)h) << 16;
    return __builtin_bit_cast(float, u);
}
__device__ __forceinline__ float lo16f(unsigned int u) {
    return __builtin_bit_cast(float, u << 16);
}
__device__ __forceinline__ float hi16f(unsigned int u) {
    return __builtin_bit_cast(float, u & 0xffff0000u);
}

__device__ __forceinline__ void gload_lds16(const void* g, void* l) {
    __builtin_amdgcn_global_load_lds(
        (const __attribute__((address_space(1))) void*)g,
        (__attribute__((address_space(3))) void*)l, 16, 0, 0);
}

// ---- feature pre-embed into hi/lo planes ----
__global__ __launch_bounds__(256) void k_pre(
    const float* __restrict__ x,
    const float* __restrict__ Wnum, const float* __restrict__ bnum,
    const float* __restrict__ Wcat, const float* __restrict__ bcat,
    unsigned short* __restrict__ hi, unsigned short* __restrict__ lo, int N)
{
    int gid = blockIdx.x * 256 + threadIdx.x;
    if (gid >= N * 128) return;
    int n = gid >> 7, k = gid & 127;
    const float* xr = x + n * 8;
    float acc;
    if (k < 64) {
        acc = bnum[k];
        #pragma unroll
        for (int p = 0; p < 5; ++p) acc += xr[p] * Wnum[p * 64 + k];
    } else {
        int kk = k - 64;
        acc = bcat[kk];
        #pragma unroll
        for (int p = 0; p < 3; ++p) acc += xr[5 + p] * Wcat[p * 64 + kk];
    }
    float v = acc >= 0.f ? acc : 0.01f * acc;
    unsigned short h = f2bf(v);
    hi[gid] = h;
    lo[gid] = f2bf(v - bf2f(h));
}

// ---- weight split+transpose: out[n][k] planes from W[k][n], 8 parts ----
struct WArgs {
    const float* W[8];
    unsigned short* hi[8];
    unsigned short* lo[8];
};
__global__ __launch_bounds__(256) void k_wsplit(WArgs a)
{
    int part = blockIdx.y;
    int idx = blockIdx.x * 256 + threadIdx.x;   // 16384 per part
    int n = idx >> 7, k = idx & 127;
    float v = a.W[part][(size_t)k * 128 + n];
    unsigned short h = f2bf(v);
    a.hi[part][(size_t)n * 128 + k] = h;
    a.lo[part][(size_t)n * 128 + k] = f2bf(v - bf2f(h));
}

// ---- CSR build: rank pass (4 edges/thread, coalesced rank store) ----
__global__ __launch_bounds__(256) void k_rank(
    const int* __restrict__ ei, const int* __restrict__ et,
    int* __restrict__ deg, int* __restrict__ rank, int E, int N)
{
    int base = blockIdx.x * 1024 + threadIdx.x;
    int e0 = base, e1 = base + 256, e2 = base + 512, e3 = base + 768;
    int r0 = 0, r1 = 0, r2 = 0, r3 = 0;
    if (e0 < E) r0 = atomicAdd(&deg[et[e0] * N + ei[E + e0]], 1);
    if (e1 < E) r1 = atomicAdd(&deg[et[e1] * N + ei[E + e1]], 1);
    if (e2 < E) r2 = atomicAdd(&deg[et[e2] * N + ei[E + e2]], 1);
    if (e3 < E) r3 = atomicAdd(&deg[et[e3] * N + ei[E + e3]], 1);
    if (e0 < E) rank[e0] = r0;
    if (e1 < E) rank[e1] = r1;
    if (e2 < E) rank[e2] = r2;
    if (e3 < E) rank[e3] = r3;
}

__global__ __launch_bounds__(256) void k_scan1(
    const int* __restrict__ deg, int* __restrict__ off,
    int* __restrict__ bsum, int n)
{
    __shared__ int s[256];
    int t = threadIdx.x;
    int i = blockIdx.x * 256 + t;
    int v = (i < n) ? deg[i] : 0;
    s[t] = v;
    __syncthreads();
    #pragma unroll
    for (int d = 1; d < 256; d <<= 1) {
        int add = (t >= d) ? s[t - d] : 0;
        __syncthreads();
        s[t] += add;
        __syncthreads();
    }
    if (i < n) off[i] = s[t] - v;
    if (t == 255) bsum[blockIdx.x] = s[255];
}

__global__ __launch_bounds__(1024) void k_scan2(int* __restrict__ bsum, int nb)
{
    __shared__ int s[1024];
    int t = threadIdx.x;
    int v = (t < nb) ? bsum[t] : 0;
    s[t] = v;
    __syncthreads();
    #pragma unroll
    for (int d = 1; d < 1024; d <<= 1) {
        int add = (t >= d) ? s[t - d] : 0;
        __syncthreads();
        s[t] += add;
        __syncthreads();
    }
    if (t < nb) bsum[t] = s[t] - v;
}

__global__ __launch_bounds__(256) void k_scan3(
    int* __restrict__ off, const int* __restrict__ bsum, int n)
{
    int i = blockIdx.x * 256 + threadIdx.x;
    if (i < n) off[i] += bsum[blockIdx.x];
}

// ---- CSR build: atomic-free scatter (4 edges/thread) ----
__global__ __launch_bounds__(256) void k_scatter(
    const int* __restrict__ ei, const int* __restrict__ et,
    const int* __restrict__ off, const int* __restrict__ rank,
    int* __restrict__ esrc, int E, int N)
{
    int base = blockIdx.x * 1024 + threadIdx.x;
    #pragma unroll
    for (int j = 0; j < 4; ++j) {
        int e = base + j * 256;
        if (e < E) {
            int seg = et[e] * N + ei[E + e];
            esrc[off[seg] + rank[e]] = ei[e];
        }
    }
}

// ---- mean aggregation, bf16 hi plane only ----
__global__ __launch_bounds__(256) void k_gather(
    const unsigned short* __restrict__ h_hi,
    const int* __restrict__ esrc,
    const int* __restrict__ off, const int* __restrict__ deg,
    unsigned short* __restrict__ a_hi, int nseg)
{
    int i = blockIdx.x * 4 + (threadIdx.x >> 6);
    if (i >= nseg) return;
    int lane = threadIdx.x & 63;
    int cnt = deg[i], st = off[i];
    const unsigned int* hp = (const unsigned int*)h_hi;   // [row][64] packed
    float sa0 = 0.f, sb0 = 0.f, sa1 = 0.f, sb1 = 0.f;
    float sa2 = 0.f, sb2 = 0.f, sa3 = 0.f, sb3 = 0.f;
    int e = 0;
    for (; e + 4 <= cnt; e += 4) {
        int i0 = esrc[st + e + 0];
        int i1 = esrc[st + e + 1];
        int i2 = esrc[st + e + 2];
        int i3 = esrc[st + e + 3];
        unsigned int u0 = hp[(size_t)i0 * 64 + lane];
        unsigned int u1 = hp[(size_t)i1 * 64 + lane];
        unsigned int u2 = hp[(size_t)i2 * 64 + lane];
        unsigned int u3 = hp[(size_t)i3 * 64 + lane];
        sa0 += lo16f(u0); sb0 += hi16f(u0);
        sa1 += lo16f(u1); sb1 += hi16f(u1);
        sa2 += lo16f(u2); sb2 += hi16f(u2);
        sa3 += lo16f(u3); sb3 += hi16f(u3);
    }
    for (; e < cnt; ++e) {
        unsigned int u = hp[(size_t)esrc[st + e] * 64 + lane];
        sa0 += lo16f(u); sb0 += hi16f(u);
    }
    float inv = 1.0f / (float)(cnt > 1 ? cnt : 1);
    float ma = ((sa0 + sa1) + (sa2 + sa3)) * inv;
    float mb = ((sb0 + sb1) + (sb2 + sb3)) * inv;
    unsigned int outp = (unsigned int)f2bf(ma) | ((unsigned int)f2bf(mb) << 16);
    ((unsigned int*)a_hi)[(size_t)i * 64 + lane] = outp;
}

// ---- split-bf16 MFMA GEMM ----
struct GArgs {
    const unsigned short* A_hi[3];
    const unsigned short* A_lo[3];
    const unsigned short* B_hi[3];   // transposed [n][k]
    const unsigned short* B_lo[3];
    int alo[3];                      // 1 if A_lo[p] exists
    const float* bias;
    const float* prelu;              // nullable
    float* Cf;                       // if non-null: fp32 output
    unsigned short* C_hi;            // else hi/lo plane output
    unsigned short* C_lo;
    int M;
    int P;
};

__global__ __launch_bounds__(256) void k_mgemm(GArgs g)
{
    __shared__ unsigned short lds[32 * 512];   // 32 KB
    const int t = threadIdx.x;
    const int w = t >> 6, lane = t & 63;
    const int laneL = lane & 15, laneH = lane >> 4;
    const int wi = w >> 1, wj = w & 1;
    const int m0 = blockIdx.x * 128;
    const int Mm1 = g.M - 1;

    f32x4 acc[4][4];
    #pragma unroll
    for (int a = 0; a < 4; ++a)
        #pragma unroll
        for (int b = 0; b < 4; ++b)
            acc[a][b] = (f32x4){0.f, 0.f, 0.f, 0.f};

    for (int p = 0; p < g.P; ++p) {
        const bool hasAlo = g.alo[p] != 0;
        const unsigned short* plane;
        if      (w == 0) plane = g.A_hi[p];
        else if (w == 1) plane = hasAlo ? g.A_lo[p] : nullptr;
        else if (w == 2) plane = g.B_hi[p];
        else             plane = g.B_lo[p];
        const bool isA = (w < 2);

        for (int kt = 0; kt < 4; ++kt) {
            if (plane) {
                #pragma unroll
                for (int j = 0; j < 8; ++j) {
                    int rc = j * 16 + laneL;
                    int row = isA ? (m0 + rc <= Mm1 ? m0 + rc : Mm1) : rc;
                    const unsigned short* gp = plane + (size_t)row * 128 + kt * 32 + laneH * 8;
                    unsigned short* lp = &lds[(w * 8 + j) * 512];
                    gload_lds16(gp, lp);
                }
            }
            __syncthreads();

            const bf16x8* fr = (const bf16x8*)lds;
            bf16x8 ah[4], al[4], bh[4], bl[4];
            #pragma unroll
            for (int mi = 0; mi < 4; ++mi)
                ah[mi] = fr[(0 + wi * 4 + mi) * 64 + lane];
            if (hasAlo) {
                #pragma unroll
                for (int mi = 0; mi < 4; ++mi)
                    al[mi] = fr[(8 + wi * 4 + mi) * 64 + lane];
            }
            #pragma unroll
            for (int nj = 0; nj < 4; ++nj) {
                bh[nj] = fr[(16 + wj * 4 + nj) * 64 + lane];
                bl[nj] = fr[(24 + wj * 4 + nj) * 64 + lane];
            }
            #pragma unroll
            for (int mi = 0; mi < 4; ++mi)
                #pragma unroll
                for (int nj = 0; nj < 4; ++nj) {
                    acc[mi][nj] = __builtin_amdgcn_mfma_f32_16x16x32_bf16(
                        ah[mi], bh[nj], acc[mi][nj], 0, 0, 0);
                    acc[mi][nj] = __builtin_amdgcn_mfma_f32_16x16x32_bf16(
                        ah[mi], bl[nj], acc[mi][nj], 0, 0, 0);
                    if (hasAlo)
                        acc[mi][nj] = __builtin_amdgcn_mfma_f32_16x16x32_bf16(
                            al[mi], bh[nj], acc[mi][nj], 0, 0, 0);
                }
            __syncthreads();
        }
    }

    const bool hasPrelu = (g.prelu != nullptr);
    const bool outF32 = (g.Cf != nullptr);
    #pragma unroll
    for (int nj = 0; nj < 4; ++nj) {
        int col = wj * 64 + nj * 16 + laneL;
        float bv = g.bias[col];
        float av = hasPrelu ? g.prelu[col] : 0.f;
        #pragma unroll
        for (int mi = 0; mi < 4; ++mi) {
            #pragma unroll
            for (int r = 0; r < 4; ++r) {
                int m = m0 + wi * 64 + mi * 16 + laneH * 4 + r;
                if (m >= g.M) continue;
                float v = acc[mi][nj][r] + bv;
                if (hasPrelu) v = v >= 0.f ? v : av * v;
                size_t idx = (size_t)m * 128 + col;
                if (outF32) {
                    g.Cf[idx] = v;
                } else {
                    unsigned short h = f2bf(v);
                    g.C_hi[idx] = h;
                    g.C_lo[idx] = f2bf(v - bf2f(h));
                }
            }
        }
    }
}

extern "C" void kernel_launch(void* const* d_in, const int* in_sizes, int n_in,
                              void* d_out, int out_size, void* d_ws, size_t ws_size,
                              hipStream_t stream) {
    const float* x      = (const float*)d_in[0];
    const int*   ei     = (const int*)d_in[1];
    const int*   et     = (const int*)d_in[2];
    const float* Wnum   = (const float*)d_in[3];
    const float* bnum   = (const float*)d_in[4];
    const float* Wcat   = (const float*)d_in[5];
    const float* bcat   = (const float*)d_in[6];
    const float* Win    = (const float*)d_in[7];
    const float* bin    = (const float*)d_in[8];
    const float* pa     = (const float*)d_in[9];
    const float* Wrel1  = (const float*)d_in[10];
    const float* Wroot1 = (const float*)d_in[11];
    const float* brg1   = (const float*)d_in[12];
    const float* Wrel2  = (const float*)d_in[13];
    const float* Wroot2 = (const float*)d_in[14];
    const float* brg2   = (const float*)d_in[15];
    const float* Wcls   = (const float*)d_in[16];
    const float* bcls   = (const float*)d_in[17];
    float* out = (float*)d_out;

    const int N = in_sizes[0] / 8;
    const int E = in_sizes[1] / 2;
    const int nseg = 2 * N;
    const size_t NH = (size_t)N * 128;

    // ---- workspace carve-up ----
    char* w = (char*)d_ws;
    unsigned short* h0_hi = (unsigned short*)w;  w += NH * 2;
    unsigned short* h0_lo = (unsigned short*)w;  w += NH * 2;
    unsigned short* agg_hi = (unsigned short*)w; w += 2 * NH * 2;
    int* deg  = (int*)w;  w += (size_t)nseg * 4;
    int* off  = (int*)w;  w += (size_t)nseg * 4;
    int* rank = (int*)w;  w += (size_t)E * 4;
    int* esrc = (int*)w;  w += (size_t)E * 4;
    int* bsum = (int*)w;  w += 1024 * 4;
    unsigned short* wplanes = (unsigned short*)w;  w += 8 * 2 * 16384 * 2;

    unsigned short* hp_hi = agg_hi;
    unsigned short* hp_lo = agg_hi + NH;
    unsigned short* h1_hi = (unsigned short*)d_out;
    unsigned short* h1_lo = h1_hi + NH;
    unsigned short* h2_hi = h0_hi;
    unsigned short* h2_lo = h0_lo;

    unsigned short* whi[8];
    unsigned short* wlo[8];
    for (int i = 0; i < 8; ++i) {
        whi[i] = wplanes + (size_t)i * 2 * 16384;
        wlo[i] = whi[i] + 16384;
    }

    hipMemsetAsync(deg, 0, (size_t)nseg * sizeof(int), stream);

    {
        WArgs a;
        a.W[0] = Win;   a.W[1] = Wroot1; a.W[2] = Wrel1; a.W[3] = Wrel1 + 16384;
        a.W[4] = Wroot2; a.W[5] = Wrel2; a.W[6] = Wrel2 + 16384; a.W[7] = Wcls;
        for (int i = 0; i < 8; ++i) { a.hi[i] = whi[i]; a.lo[i] = wlo[i]; }
        k_wsplit<<<dim3(64, 8), 256, 0, stream>>>(a);
    }

    const int nb = (nseg + 255) / 256;
    const int gE4 = (E + 1023) / 1024;
    const int gm = (N + 127) / 128;
    const int gg = (nseg + 3) / 4;

    k_pre<<<(N * 128 + 255) / 256, 256, 0, stream>>>(x, Wnum, bnum, Wcat, bcat, hp_hi, hp_lo, N);
    k_rank<<<gE4, 256, 0, stream>>>(ei, et, deg, rank, E, N);
    k_scan1<<<nb, 256, 0, stream>>>(deg, off, bsum, nseg);
    k_scan2<<<1, 1024, 0, stream>>>(bsum, nb);
    k_scan3<<<nb, 256, 0, stream>>>(off, bsum, nseg);
    k_scatter<<<gE4, 256, 0, stream>>>(ei, et, off, rank, esrc, E, N);

    // embed: h0 = prelu(hpre @ W_in + b_in)
    {
        GArgs g = {};
        g.A_hi[0] = hp_hi; g.A_lo[0] = hp_lo; g.alo[0] = 1;
        g.B_hi[0] = whi[0]; g.B_lo[0] = wlo[0];
        g.bias = bin; g.prelu = pa;
        g.Cf = nullptr; g.C_hi = h0_hi; g.C_lo = h0_lo;
        g.M = N; g.P = 1;
        k_mgemm<<<gm, 256, 0, stream>>>(g);
    }
    // layer 1
    k_gather<<<gg, 256, 0, stream>>>(h0_hi, esrc, off, deg, agg_hi, nseg);
    {
        GArgs g = {};
        g.A_hi[0] = h0_hi;       g.A_lo[0] = h0_lo;  g.alo[0] = 1;
        g.A_hi[1] = agg_hi;      g.alo[1] = 0;
        g.A_hi[2] = agg_hi + NH; g.alo[2] = 0;
        g.B_hi[0] = whi[1]; g.B_lo[0] = wlo[1];
        g.B_hi[1] = whi[2]; g.B_lo[1] = wlo[2];
        g.B_hi[2] = whi[3]; g.B_lo[2] = wlo[3];
        g.bias = brg1; g.prelu = nullptr;
        g.Cf = nullptr; g.C_hi = h1_hi; g.C_lo = h1_lo;
        g.M = N; g.P = 3;
        k_mgemm<<<gm, 256, 0, stream>>>(g);
    }
    // layer 2
    k_gather<<<gg, 256, 0, stream>>>(h1_hi, esrc, off, deg, agg_hi, nseg);
    {
        GArgs g = {};
        g.A_hi[0] = h1_hi;       g.A_lo[0] = h1_lo;  g.alo[0] = 1;
        g.A_hi[1] = agg_hi;      g.alo[1] = 0;
        g.A_hi[2] = agg_hi + NH; g.alo[2] = 0;
        g.B_hi[0] = whi[4]; g.B_lo[0] = wlo[4];
        g.B_hi[1] = whi[5]; g.B_lo[1] = wlo[5];
        g.B_hi[2] = whi[6]; g.B_lo[2] = wlo[6];
        g.bias = brg2; g.prelu = nullptr;
        g.Cf = nullptr; g.C_hi = h2_hi; g.C_lo = h2_lo;
        g.M = N; g.P = 3;
        k_mgemm<<<gm, 256, 0, stream>>>(g);
    }
    // classifier -> fp32 out
    {
        GArgs g = {};
        g.A_hi[0] = h2_hi; g.A_lo[0] = h2_lo; g.alo[0] = 1;
        g.B_hi[0] = whi[7]; g.B_lo[0] = wlo[7];
        g.bias = bcls; g.prelu = nullptr;
        g.Cf = out; g.C_hi = nullptr; g.C_lo = nullptr;
        g.M = N; g.P = 1;
        k_mgemm<<<gm, 256, 0, stream>>>(g);
    }
}

// Round 5
// 640.661 us; speedup vs baseline: 1.6374x; 1.0384x over previous
//
#include <hip/hip_runtime.h>
#include <cstdint>

// ---------------------------------------------------------------------------
// BotRGCN round 5: split-bf16 MFMA GEMMs + 2-edge-per-wave gather + batched CSR.
// - Gather: half-wave (32 lanes x uint2) per edge row, 8 edges in flight/wave.
// - CSR: 8 edges/thread rank+scatter (latency-bound -> more MLP).
// - GEMM: agg parts use Ah*Bh only (error budget: absmax floor 2^-12 observed).
// ---------------------------------------------------------------------------

typedef short bf16x8 __attribute__((ext_vector_type(8)));
typedef float f32x4  __attribute__((ext_vector_type(4)));

__device__ __forceinline__ unsigned short f2bf(float f) {
    unsigned int u = __builtin_bit_cast(unsigned int, f);
    u += 0x7fff + ((u >> 16) & 1);          // RNE
    return (unsigned short)(u >> 16);
}
__device__ __forceinline__ float bf2f(unsigned short h) {
    unsigned int u = ((unsigned int)h) << 16;
    return __builtin_bit_cast(float, u);
}
__device__ __forceinline__ float lo16f(unsigned int u) {
    return __builtin_bit_cast(float, u << 16);
}
__device__ __forceinline__ float hi16f(unsigned int u) {
    return __builtin_bit_cast(float, u & 0xffff0000u);
}

__device__ __forceinline__ void gload_lds16(const void* g, void* l) {
    __builtin_amdgcn_global_load_lds(
        (const __attribute__((address_space(1))) void*)g,
        (__attribute__((address_space(3))) void*)l, 16, 0, 0);
}

// ---- feature pre-embed into hi/lo planes ----
__global__ __launch_bounds__(256) void k_pre(
    const float* __restrict__ x,
    const float* __restrict__ Wnum, const float* __restrict__ bnum,
    const float* __restrict__ Wcat, const float* __restrict__ bcat,
    unsigned short* __restrict__ hi, unsigned short* __restrict__ lo, int N)
{
    int gid = blockIdx.x * 256 + threadIdx.x;
    if (gid >= N * 128) return;
    int n = gid >> 7, k = gid & 127;
    const float* xr = x + n * 8;
    float acc;
    if (k < 64) {
        acc = bnum[k];
        #pragma unroll
        for (int p = 0; p < 5; ++p) acc += xr[p] * Wnum[p * 64 + k];
    } else {
        int kk = k - 64;
        acc = bcat[kk];
        #pragma unroll
        for (int p = 0; p < 3; ++p) acc += xr[5 + p] * Wcat[p * 64 + kk];
    }
    float v = acc >= 0.f ? acc : 0.01f * acc;
    unsigned short h = f2bf(v);
    hi[gid] = h;
    lo[gid] = f2bf(v - bf2f(h));
}

// ---- weight split+transpose: out[n][k] planes from W[k][n], 8 parts ----
struct WArgs {
    const float* W[8];
    unsigned short* hi[8];
    unsigned short* lo[8];
};
__global__ __launch_bounds__(256) void k_wsplit(WArgs a)
{
    int part = blockIdx.y;
    int idx = blockIdx.x * 256 + threadIdx.x;   // 16384 per part
    int n = idx >> 7, k = idx & 127;
    float v = a.W[part][(size_t)k * 128 + n];
    unsigned short h = f2bf(v);
    a.hi[part][(size_t)n * 128 + k] = h;
    a.lo[part][(size_t)n * 128 + k] = f2bf(v - bf2f(h));
}

// ---- CSR build: rank pass (8 edges/thread, coalesced rank store) ----
__global__ __launch_bounds__(256) void k_rank(
    const int* __restrict__ ei, const int* __restrict__ et,
    int* __restrict__ deg, int* __restrict__ rank, int E, int N)
{
    int base = blockIdx.x * 2048 + threadIdx.x;
    int e[8], r[8];
    #pragma unroll
    for (int j = 0; j < 8; ++j) {
        e[j] = base + j * 256;
        r[j] = 0;
        if (e[j] < E) r[j] = atomicAdd(&deg[et[e[j]] * N + ei[E + e[j]]], 1);
    }
    #pragma unroll
    for (int j = 0; j < 8; ++j)
        if (e[j] < E) rank[e[j]] = r[j];
}

__global__ __launch_bounds__(256) void k_scan1(
    const int* __restrict__ deg, int* __restrict__ off,
    int* __restrict__ bsum, int n)
{
    __shared__ int s[256];
    int t = threadIdx.x;
    int i = blockIdx.x * 256 + t;
    int v = (i < n) ? deg[i] : 0;
    s[t] = v;
    __syncthreads();
    #pragma unroll
    for (int d = 1; d < 256; d <<= 1) {
        int add = (t >= d) ? s[t - d] : 0;
        __syncthreads();
        s[t] += add;
        __syncthreads();
    }
    if (i < n) off[i] = s[t] - v;
    if (t == 255) bsum[blockIdx.x] = s[255];
}

__global__ __launch_bounds__(1024) void k_scan2(int* __restrict__ bsum, int nb)
{
    __shared__ int s[1024];
    int t = threadIdx.x;
    int v = (t < nb) ? bsum[t] : 0;
    s[t] = v;
    __syncthreads();
    #pragma unroll
    for (int d = 1; d < 1024; d <<= 1) {
        int add = (t >= d) ? s[t - d] : 0;
        __syncthreads();
        s[t] += add;
        __syncthreads();
    }
    if (t < nb) bsum[t] = s[t] - v;
}

__global__ __launch_bounds__(256) void k_scan3(
    int* __restrict__ off, const int* __restrict__ bsum, int n)
{
    int i = blockIdx.x * 256 + threadIdx.x;
    if (i < n) off[i] += bsum[blockIdx.x];
}

// ---- CSR build: atomic-free scatter (8 edges/thread) ----
__global__ __launch_bounds__(256) void k_scatter(
    const int* __restrict__ ei, const int* __restrict__ et,
    const int* __restrict__ off, const int* __restrict__ rank,
    int* __restrict__ esrc, int E, int N)
{
    int base = blockIdx.x * 2048 + threadIdx.x;
    #pragma unroll
    for (int j = 0; j < 8; ++j) {
        int e = base + j * 256;
        if (e < E) {
            int seg = et[e] * N + ei[E + e];
            esrc[off[seg] + rank[e]] = ei[e];
        }
    }
}

// ---- mean aggregation, bf16 hi plane only ----
// One wave per segment; half-wave (32 lanes x uint2 = 256 B) per edge row.
// Half 0 takes even edge indices, half 1 odd; 4-deep unroll per half
// -> 8 edges in flight per wave. Cross-half combine via shfl_xor(32).
__global__ __launch_bounds__(256) void k_gather(
    const unsigned short* __restrict__ h_hi,
    const int* __restrict__ esrc,
    const int* __restrict__ off, const int* __restrict__ deg,
    unsigned short* __restrict__ a_hi, int nseg)
{
    int i = blockIdx.x * 4 + (threadIdx.x >> 6);
    if (i >= nseg) return;
    int lane = threadIdx.x & 63;
    int half = lane >> 5, l32 = lane & 31;
    int cnt = deg[i], st = off[i];
    const uint2* hp = (const uint2*)h_hi;   // row = 32 x uint2 (4 bf16 feats)
    float s0 = 0.f, s1 = 0.f, s2 = 0.f, s3 = 0.f;
    float t0 = 0.f, t1 = 0.f, t2 = 0.f, t3 = 0.f;
    int e = half;
    for (; e + 6 < cnt; e += 8) {
        int i0 = esrc[st + e + 0];
        int i1 = esrc[st + e + 2];
        int i2 = esrc[st + e + 4];
        int i3 = esrc[st + e + 6];
        uint2 u0 = hp[(size_t)i0 * 32 + l32];
        uint2 u1 = hp[(size_t)i1 * 32 + l32];
        uint2 u2 = hp[(size_t)i2 * 32 + l32];
        uint2 u3 = hp[(size_t)i3 * 32 + l32];
        s0 += lo16f(u0.x); s1 += hi16f(u0.x); s2 += lo16f(u0.y); s3 += hi16f(u0.y);
        t0 += lo16f(u1.x); t1 += hi16f(u1.x); t2 += lo16f(u1.y); t3 += hi16f(u1.y);
        s0 += lo16f(u2.x); s1 += hi16f(u2.x); s2 += lo16f(u2.y); s3 += hi16f(u2.y);
        t0 += lo16f(u3.x); t1 += hi16f(u3.x); t2 += lo16f(u3.y); t3 += hi16f(u3.y);
    }
    for (; e < cnt; e += 2) {
        uint2 u = hp[(size_t)esrc[st + e] * 32 + l32];
        s0 += lo16f(u.x); s1 += hi16f(u.x); s2 += lo16f(u.y); s3 += hi16f(u.y);
    }
    s0 += t0; s1 += t1; s2 += t2; s3 += t3;
    s0 += __shfl_xor(s0, 32, 64);
    s1 += __shfl_xor(s1, 32, 64);
    s2 += __shfl_xor(s2, 32, 64);
    s3 += __shfl_xor(s3, 32, 64);
    if (half == 0) {
        float inv = 1.0f / (float)(cnt > 1 ? cnt : 1);
        uint2 o;
        o.x = (unsigned int)f2bf(s0 * inv) | ((unsigned int)f2bf(s1 * inv) << 16);
        o.y = (unsigned int)f2bf(s2 * inv) | ((unsigned int)f2bf(s3 * inv) << 16);
        ((uint2*)a_hi)[(size_t)i * 32 + l32] = o;
    }
}

// ---- split-bf16 MFMA GEMM ----
// Per part p: Ah*Bh (+ Ah*Bl if blo[p]) (+ Al*Bh if alo[p]).
struct GArgs {
    const unsigned short* A_hi[3];
    const unsigned short* A_lo[3];
    const unsigned short* B_hi[3];   // transposed [n][k]
    const unsigned short* B_lo[3];
    int alo[3];                      // 1 if A_lo[p] exists
    int blo[3];                      // 1 if B_lo[p] term included
    const float* bias;
    const float* prelu;              // nullable
    float* Cf;                       // if non-null: fp32 output
    unsigned short* C_hi;            // else hi/lo plane output
    unsigned short* C_lo;
    int M;
    int P;
};

__global__ __launch_bounds__(256) void k_mgemm(GArgs g)
{
    __shared__ unsigned short lds[32 * 512];   // 32 KB
    const int t = threadIdx.x;
    const int w = t >> 6, lane = t & 63;
    const int laneL = lane & 15, laneH = lane >> 4;
    const int wi = w >> 1, wj = w & 1;
    const int m0 = blockIdx.x * 128;
    const int Mm1 = g.M - 1;

    f32x4 acc[4][4];
    #pragma unroll
    for (int a = 0; a < 4; ++a)
        #pragma unroll
        for (int b = 0; b < 4; ++b)
            acc[a][b] = (f32x4){0.f, 0.f, 0.f, 0.f};

    for (int p = 0; p < g.P; ++p) {
        const bool hasAlo = g.alo[p] != 0;
        const bool hasBlo = g.blo[p] != 0;
        const unsigned short* plane;
        if      (w == 0) plane = g.A_hi[p];
        else if (w == 1) plane = hasAlo ? g.A_lo[p] : nullptr;
        else if (w == 2) plane = g.B_hi[p];
        else             plane = hasBlo ? g.B_lo[p] : nullptr;
        const bool isA = (w < 2);

        for (int kt = 0; kt < 4; ++kt) {
            if (plane) {
                #pragma unroll
                for (int j = 0; j < 8; ++j) {
                    int rc = j * 16 + laneL;
                    int row = isA ? (m0 + rc <= Mm1 ? m0 + rc : Mm1) : rc;
                    const unsigned short* gp = plane + (size_t)row * 128 + kt * 32 + laneH * 8;
                    unsigned short* lp = &lds[(w * 8 + j) * 512];
                    gload_lds16(gp, lp);
                }
            }
            __syncthreads();

            const bf16x8* fr = (const bf16x8*)lds;
            bf16x8 ah[4], al[4], bh[4], bl[4];
            #pragma unroll
            for (int mi = 0; mi < 4; ++mi)
                ah[mi] = fr[(0 + wi * 4 + mi) * 64 + lane];
            if (hasAlo) {
                #pragma unroll
                for (int mi = 0; mi < 4; ++mi)
                    al[mi] = fr[(8 + wi * 4 + mi) * 64 + lane];
            }
            #pragma unroll
            for (int nj = 0; nj < 4; ++nj)
                bh[nj] = fr[(16 + wj * 4 + nj) * 64 + lane];
            if (hasBlo) {
                #pragma unroll
                for (int nj = 0; nj < 4; ++nj)
                    bl[nj] = fr[(24 + wj * 4 + nj) * 64 + lane];
            }
            #pragma unroll
            for (int mi = 0; mi < 4; ++mi)
                #pragma unroll
                for (int nj = 0; nj < 4; ++nj) {
                    acc[mi][nj] = __builtin_amdgcn_mfma_f32_16x16x32_bf16(
                        ah[mi], bh[nj], acc[mi][nj], 0, 0, 0);
                    if (hasBlo)
                        acc[mi][nj] = __builtin_amdgcn_mfma_f32_16x16x32_bf16(
                            ah[mi], bl[nj], acc[mi][nj], 0, 0, 0);
                    if (hasAlo)
                        acc[mi][nj] = __builtin_amdgcn_mfma_f32_16x16x32_bf16(
                            al[mi], bh[nj], acc[mi][nj], 0, 0, 0);
                }
            __syncthreads();
        }
    }

    const bool hasPrelu = (g.prelu != nullptr);
    const bool outF32 = (g.Cf != nullptr);
    #pragma unroll
    for (int nj = 0; nj < 4; ++nj) {
        int col = wj * 64 + nj * 16 + laneL;
        float bv = g.bias[col];
        float av = hasPrelu ? g.prelu[col] : 0.f;
        #pragma unroll
        for (int mi = 0; mi < 4; ++mi) {
            #pragma unroll
            for (int r = 0; r < 4; ++r) {
                int m = m0 + wi * 64 + mi * 16 + laneH * 4 + r;
                if (m >= g.M) continue;
                float v = acc[mi][nj][r] + bv;
                if (hasPrelu) v = v >= 0.f ? v : av * v;
                size_t idx = (size_t)m * 128 + col;
                if (outF32) {
                    g.Cf[idx] = v;
                } else {
                    unsigned short h = f2bf(v);
                    g.C_hi[idx] = h;
                    g.C_lo[idx] = f2bf(v - bf2f(h));
                }
            }
        }
    }
}

extern "C" void kernel_launch(void* const* d_in, const int* in_sizes, int n_in,
                              void* d_out, int out_size, void* d_ws, size_t ws_size,
                              hipStream_t stream) {
    const float* x      = (const float*)d_in[0];
    const int*   ei     = (const int*)d_in[1];
    const int*   et     = (const int*)d_in[2];
    const float* Wnum   = (const float*)d_in[3];
    const float* bnum   = (const float*)d_in[4];
    const float* Wcat   = (const float*)d_in[5];
    const float* bcat   = (const float*)d_in[6];
    const float* Win    = (const float*)d_in[7];
    const float* bin    = (const float*)d_in[8];
    const float* pa     = (const float*)d_in[9];
    const float* Wrel1  = (const float*)d_in[10];
    const float* Wroot1 = (const float*)d_in[11];
    const float* brg1   = (const float*)d_in[12];
    const float* Wrel2  = (const float*)d_in[13];
    const float* Wroot2 = (const float*)d_in[14];
    const float* brg2   = (const float*)d_in[15];
    const float* Wcls   = (const float*)d_in[16];
    const float* bcls   = (const float*)d_in[17];
    float* out = (float*)d_out;

    const int N = in_sizes[0] / 8;
    const int E = in_sizes[1] / 2;
    const int nseg = 2 * N;
    const size_t NH = (size_t)N * 128;

    // ---- workspace carve-up ----
    char* w = (char*)d_ws;
    unsigned short* h0_hi = (unsigned short*)w;  w += NH * 2;
    unsigned short* h0_lo = (unsigned short*)w;  w += NH * 2;
    unsigned short* agg_hi = (unsigned short*)w; w += 2 * NH * 2;
    int* deg  = (int*)w;  w += (size_t)nseg * 4;
    int* off  = (int*)w;  w += (size_t)nseg * 4;
    int* rank = (int*)w;  w += (size_t)E * 4;
    int* esrc = (int*)w;  w += (size_t)E * 4;
    int* bsum = (int*)w;  w += 1024 * 4;
    unsigned short* wplanes = (unsigned short*)w;  w += 8 * 2 * 16384 * 2;

    unsigned short* hp_hi = agg_hi;
    unsigned short* hp_lo = agg_hi + NH;
    unsigned short* h1_hi = (unsigned short*)d_out;
    unsigned short* h1_lo = h1_hi + NH;
    unsigned short* h2_hi = h0_hi;
    unsigned short* h2_lo = h0_lo;

    unsigned short* whi[8];
    unsigned short* wlo[8];
    for (int i = 0; i < 8; ++i) {
        whi[i] = wplanes + (size_t)i * 2 * 16384;
        wlo[i] = whi[i] + 16384;
    }

    hipMemsetAsync(deg, 0, (size_t)nseg * sizeof(int), stream);

    {
        WArgs a;
        a.W[0] = Win;   a.W[1] = Wroot1; a.W[2] = Wrel1; a.W[3] = Wrel1 + 16384;
        a.W[4] = Wroot2; a.W[5] = Wrel2; a.W[6] = Wrel2 + 16384; a.W[7] = Wcls;
        for (int i = 0; i < 8; ++i) { a.hi[i] = whi[i]; a.lo[i] = wlo[i]; }
        k_wsplit<<<dim3(64, 8), 256, 0, stream>>>(a);
    }

    const int nb = (nseg + 255) / 256;
    const int gE8 = (E + 2047) / 2048;
    const int gm = (N + 127) / 128;
    const int gg = (nseg + 3) / 4;

    k_pre<<<(N * 128 + 255) / 256, 256, 0, stream>>>(x, Wnum, bnum, Wcat, bcat, hp_hi, hp_lo, N);
    k_rank<<<gE8, 256, 0, stream>>>(ei, et, deg, rank, E, N);
    k_scan1<<<nb, 256, 0, stream>>>(deg, off, bsum, nseg);
    k_scan2<<<1, 1024, 0, stream>>>(bsum, nb);
    k_scan3<<<nb, 256, 0, stream>>>(off, bsum, nseg);
    k_scatter<<<gE8, 256, 0, stream>>>(ei, et, off, rank, esrc, E, N);

    // embed: h0 = prelu(hpre @ W_in + b_in)
    {
        GArgs g = {};
        g.A_hi[0] = hp_hi; g.A_lo[0] = hp_lo; g.alo[0] = 1; g.blo[0] = 1;
        g.B_hi[0] = whi[0]; g.B_lo[0] = wlo[0];
        g.bias = bin; g.prelu = pa;
        g.Cf = nullptr; g.C_hi = h0_hi; g.C_lo = h0_lo;
        g.M = N; g.P = 1;
        k_mgemm<<<gm, 256, 0, stream>>>(g);
    }
    // layer 1
    k_gather<<<gg, 256, 0, stream>>>(h0_hi, esrc, off, deg, agg_hi, nseg);
    {
        GArgs g = {};
        g.A_hi[0] = h0_hi;       g.A_lo[0] = h0_lo;  g.alo[0] = 1; g.blo[0] = 1;
        g.A_hi[1] = agg_hi;      g.alo[1] = 0;       g.blo[1] = 0;
        g.A_hi[2] = agg_hi + NH; g.alo[2] = 0;       g.blo[2] = 0;
        g.B_hi[0] = whi[1]; g.B_lo[0] = wlo[1];
        g.B_hi[1] = whi[2]; g.B_lo[1] = wlo[2];
        g.B_hi[2] = whi[3]; g.B_lo[2] = wlo[3];
        g.bias = brg1; g.prelu = nullptr;
        g.Cf = nullptr; g.C_hi = h1_hi; g.C_lo = h1_lo;
        g.M = N; g.P = 3;
        k_mgemm<<<gm, 256, 0, stream>>>(g);
    }
    // layer 2
    k_gather<<<gg, 256, 0, stream>>>(h1_hi, esrc, off, deg, agg_hi, nseg);
    {
        GArgs g = {};
        g.A_hi[0] = h1_hi;       g.A_lo[0] = h1_lo;  g.alo[0] = 1; g.blo[0] = 1;
        g.A_hi[1] = agg_hi;      g.alo[1] = 0;       g.blo[1] = 0;
        g.A_hi[2] = agg_hi + NH; g.alo[2] = 0;       g.blo[2] = 0;
        g.B_hi[0] = whi[4]; g.B_lo[0] = wlo[4];
        g.B_hi[1] = whi[5]; g.B_lo[1] = wlo[5];
        g.B_hi[2] = whi[6]; g.B_lo[2] = wlo[6];
        g.bias = brg2; g.prelu = nullptr;
        g.Cf = nullptr; g.C_hi = h2_hi; g.C_lo = h2_lo;
        g.M = N; g.P = 3;
        k_mgemm<<<gm, 256, 0, stream>>>(g);
    }
    // classifier -> fp32 out
    {
        GArgs g = {};
        g.A_hi[0] = h2_hi; g.A_lo[0] = h2_lo; g.alo[0] = 1; g.blo[0] = 1;
        g.B_hi[0] = whi[7]; g.B_lo[0] = wlo[7];
        g.bias = bcls; g.prelu = nullptr;
        g.Cf = out; g.C_hi = nullptr; g.C_lo = nullptr;
        g.M = N; g.P = 1;
        k_mgemm<<<gm, 256, 0, stream>>>(g);
    }
}

// Round 6
// 609.259 us; speedup vs baseline: 1.7218x; 1.0515x over previous
//
#include <hip/hip_runtime.h>
#include <cstdint>

// ---------------------------------------------------------------------------
// BotRGCN round 6: quarter-wave gather (16-lane uint4 rows, 16 rows in flight
// per wave at median degree). Split-bf16 MFMA GEMMs + batched CSR unchanged.
// ---------------------------------------------------------------------------

typedef short bf16x8 __attribute__((ext_vector_type(8)));
typedef float f32x4  __attribute__((ext_vector_type(4)));

__device__ __forceinline__ unsigned short f2bf(float f) {
    unsigned int u = __builtin_bit_cast(unsigned int, f);
    u += 0x7fff + ((u >> 16) & 1);          // RNE
    return (unsigned short)(u >> 16);
}
__device__ __forceinline__ float bf2f(unsigned short h) {
    unsigned int u = ((unsigned int)h) << 16;
    return __builtin_bit_cast(float, u);
}
__device__ __forceinline__ float lo16f(unsigned int u) {
    return __builtin_bit_cast(float, u << 16);
}
__device__ __forceinline__ float hi16f(unsigned int u) {
    return __builtin_bit_cast(float, u & 0xffff0000u);
}

__device__ __forceinline__ void gload_lds16(const void* g, void* l) {
    __builtin_amdgcn_global_load_lds(
        (const __attribute__((address_space(1))) void*)g,
        (__attribute__((address_space(3))) void*)l, 16, 0, 0);
}

// ---- feature pre-embed into hi/lo planes ----
__global__ __launch_bounds__(256) void k_pre(
    const float* __restrict__ x,
    const float* __restrict__ Wnum, const float* __restrict__ bnum,
    const float* __restrict__ Wcat, const float* __restrict__ bcat,
    unsigned short* __restrict__ hi, unsigned short* __restrict__ lo, int N)
{
    int gid = blockIdx.x * 256 + threadIdx.x;
    if (gid >= N * 128) return;
    int n = gid >> 7, k = gid & 127;
    const float* xr = x + n * 8;
    float acc;
    if (k < 64) {
        acc = bnum[k];
        #pragma unroll
        for (int p = 0; p < 5; ++p) acc += xr[p] * Wnum[p * 64 + k];
    } else {
        int kk = k - 64;
        acc = bcat[kk];
        #pragma unroll
        for (int p = 0; p < 3; ++p) acc += xr[5 + p] * Wcat[p * 64 + kk];
    }
    float v = acc >= 0.f ? acc : 0.01f * acc;
    unsigned short h = f2bf(v);
    hi[gid] = h;
    lo[gid] = f2bf(v - bf2f(h));
}

// ---- weight split+transpose ----
struct WArgs {
    const float* W[8];
    unsigned short* hi[8];
    unsigned short* lo[8];
};
__global__ __launch_bounds__(256) void k_wsplit(WArgs a)
{
    int part = blockIdx.y;
    int idx = blockIdx.x * 256 + threadIdx.x;
    int n = idx >> 7, k = idx & 127;
    float v = a.W[part][(size_t)k * 128 + n];
    unsigned short h = f2bf(v);
    a.hi[part][(size_t)n * 128 + k] = h;
    a.lo[part][(size_t)n * 128 + k] = f2bf(v - bf2f(h));
}

// ---- CSR build: rank pass (8 edges/thread) ----
__global__ __launch_bounds__(256) void k_rank(
    const int* __restrict__ ei, const int* __restrict__ et,
    int* __restrict__ deg, int* __restrict__ rank, int E, int N)
{
    int base = blockIdx.x * 2048 + threadIdx.x;
    int e[8], r[8];
    #pragma unroll
    for (int j = 0; j < 8; ++j) {
        e[j] = base + j * 256;
        r[j] = 0;
        if (e[j] < E) r[j] = atomicAdd(&deg[et[e[j]] * N + ei[E + e[j]]], 1);
    }
    #pragma unroll
    for (int j = 0; j < 8; ++j)
        if (e[j] < E) rank[e[j]] = r[j];
}

__global__ __launch_bounds__(256) void k_scan1(
    const int* __restrict__ deg, int* __restrict__ off,
    int* __restrict__ bsum, int n)
{
    __shared__ int s[256];
    int t = threadIdx.x;
    int i = blockIdx.x * 256 + t;
    int v = (i < n) ? deg[i] : 0;
    s[t] = v;
    __syncthreads();
    #pragma unroll
    for (int d = 1; d < 256; d <<= 1) {
        int add = (t >= d) ? s[t - d] : 0;
        __syncthreads();
        s[t] += add;
        __syncthreads();
    }
    if (i < n) off[i] = s[t] - v;
    if (t == 255) bsum[blockIdx.x] = s[255];
}

__global__ __launch_bounds__(1024) void k_scan2(int* __restrict__ bsum, int nb)
{
    __shared__ int s[1024];
    int t = threadIdx.x;
    int v = (t < nb) ? bsum[t] : 0;
    s[t] = v;
    __syncthreads();
    #pragma unroll
    for (int d = 1; d < 1024; d <<= 1) {
        int add = (t >= d) ? s[t - d] : 0;
        __syncthreads();
        s[t] += add;
        __syncthreads();
    }
    if (t < nb) bsum[t] = s[t] - v;
}

__global__ __launch_bounds__(256) void k_scan3(
    int* __restrict__ off, const int* __restrict__ bsum, int n)
{
    int i = blockIdx.x * 256 + threadIdx.x;
    if (i < n) off[i] += bsum[blockIdx.x];
}

// ---- CSR build: atomic-free scatter (8 edges/thread) ----
__global__ __launch_bounds__(256) void k_scatter(
    const int* __restrict__ ei, const int* __restrict__ et,
    const int* __restrict__ off, const int* __restrict__ rank,
    int* __restrict__ esrc, int E, int N)
{
    int base = blockIdx.x * 2048 + threadIdx.x;
    #pragma unroll
    for (int j = 0; j < 8; ++j) {
        int e = base + j * 256;
        if (e < E) {
            int seg = et[e] * N + ei[E + e];
            esrc[off[seg] + rank[e]] = ei[e];
        }
    }
}

// ---- mean aggregation, bf16 hi plane, quarter-wave rows ----
// One segment per half-wave. Within a half, the two 16-lane quarters take
// alternating edges; each quarter loads a full 256 B row as 16 x uint4 and
// unrolls 4 deep -> up to 16 rows in flight per wave. Cross-quarter combine
// via shfl_xor(16). 8 segments per 256-thread block.
__global__ __launch_bounds__(256) void k_gather(
    const unsigned short* __restrict__ h_hi,
    const int* __restrict__ esrc,
    const int* __restrict__ off, const int* __restrict__ deg,
    unsigned short* __restrict__ a_hi, int nseg)
{
    int i = blockIdx.x * 8 + (threadIdx.x >> 5);   // segment = global half-wave
    if (i >= nseg) return;
    int l32 = threadIdx.x & 31;
    int q = l32 >> 4;         // quarter parity
    int l16 = l32 & 15;
    int cnt = deg[i], st = off[i];
    const uint4* hp = (const uint4*)h_hi;   // row = 16 x uint4 (8 bf16 feats/lane)
    float a0 = 0.f, a1 = 0.f, a2 = 0.f, a3 = 0.f;
    float a4 = 0.f, a5 = 0.f, a6 = 0.f, a7 = 0.f;
    int e = q;
    for (; e + 6 < cnt; e += 8) {
        int i0 = esrc[st + e + 0];
        int i1 = esrc[st + e + 2];
        int i2 = esrc[st + e + 4];
        int i3 = esrc[st + e + 6];
        uint4 u0 = hp[(size_t)i0 * 16 + l16];
        uint4 u1 = hp[(size_t)i1 * 16 + l16];
        uint4 u2 = hp[(size_t)i2 * 16 + l16];
        uint4 u3 = hp[(size_t)i3 * 16 + l16];
        a0 += lo16f(u0.x); a1 += hi16f(u0.x); a2 += lo16f(u0.y); a3 += hi16f(u0.y);
        a4 += lo16f(u0.z); a5 += hi16f(u0.z); a6 += lo16f(u0.w); a7 += hi16f(u0.w);
        a0 += lo16f(u1.x); a1 += hi16f(u1.x); a2 += lo16f(u1.y); a3 += hi16f(u1.y);
        a4 += lo16f(u1.z); a5 += hi16f(u1.z); a6 += lo16f(u1.w); a7 += hi16f(u1.w);
        a0 += lo16f(u2.x); a1 += hi16f(u2.x); a2 += lo16f(u2.y); a3 += hi16f(u2.y);
        a4 += lo16f(u2.z); a5 += hi16f(u2.z); a6 += lo16f(u2.w); a7 += hi16f(u2.w);
        a0 += lo16f(u3.x); a1 += hi16f(u3.x); a2 += lo16f(u3.y); a3 += hi16f(u3.y);
        a4 += lo16f(u3.z); a5 += hi16f(u3.z); a6 += lo16f(u3.w); a7 += hi16f(u3.w);
    }
    for (; e < cnt; e += 2) {
        uint4 u = hp[(size_t)esrc[st + e] * 16 + l16];
        a0 += lo16f(u.x); a1 += hi16f(u.x); a2 += lo16f(u.y); a3 += hi16f(u.y);
        a4 += lo16f(u.z); a5 += hi16f(u.z); a6 += lo16f(u.w); a7 += hi16f(u.w);
    }
    a0 += __shfl_xor(a0, 16, 64);
    a1 += __shfl_xor(a1, 16, 64);
    a2 += __shfl_xor(a2, 16, 64);
    a3 += __shfl_xor(a3, 16, 64);
    a4 += __shfl_xor(a4, 16, 64);
    a5 += __shfl_xor(a5, 16, 64);
    a6 += __shfl_xor(a6, 16, 64);
    a7 += __shfl_xor(a7, 16, 64);
    if (q == 0) {
        float inv = 1.0f / (float)(cnt > 1 ? cnt : 1);
        uint4 o;
        o.x = (unsigned int)f2bf(a0 * inv) | ((unsigned int)f2bf(a1 * inv) << 16);
        o.y = (unsigned int)f2bf(a2 * inv) | ((unsigned int)f2bf(a3 * inv) << 16);
        o.z = (unsigned int)f2bf(a4 * inv) | ((unsigned int)f2bf(a5 * inv) << 16);
        o.w = (unsigned int)f2bf(a6 * inv) | ((unsigned int)f2bf(a7 * inv) << 16);
        ((uint4*)a_hi)[(size_t)i * 16 + l16] = o;
    }
}

// ---- split-bf16 MFMA GEMM ----
struct GArgs {
    const unsigned short* A_hi[3];
    const unsigned short* A_lo[3];
    const unsigned short* B_hi[3];   // transposed [n][k]
    const unsigned short* B_lo[3];
    int alo[3];
    int blo[3];
    const float* bias;
    const float* prelu;
    float* Cf;
    unsigned short* C_hi;
    unsigned short* C_lo;
    int M;
    int P;
};

__global__ __launch_bounds__(256) void k_mgemm(GArgs g)
{
    __shared__ unsigned short lds[32 * 512];   // 32 KB
    const int t = threadIdx.x;
    const int w = t >> 6, lane = t & 63;
    const int laneL = lane & 15, laneH = lane >> 4;
    const int wi = w >> 1, wj = w & 1;
    const int m0 = blockIdx.x * 128;
    const int Mm1 = g.M - 1;

    f32x4 acc[4][4];
    #pragma unroll
    for (int a = 0; a < 4; ++a)
        #pragma unroll
        for (int b = 0; b < 4; ++b)
            acc[a][b] = (f32x4){0.f, 0.f, 0.f, 0.f};

    for (int p = 0; p < g.P; ++p) {
        const bool hasAlo = g.alo[p] != 0;
        const bool hasBlo = g.blo[p] != 0;
        const unsigned short* plane;
        if      (w == 0) plane = g.A_hi[p];
        else if (w == 1) plane = hasAlo ? g.A_lo[p] : nullptr;
        else if (w == 2) plane = g.B_hi[p];
        else             plane = hasBlo ? g.B_lo[p] : nullptr;
        const bool isA = (w < 2);

        for (int kt = 0; kt < 4; ++kt) {
            if (plane) {
                #pragma unroll
                for (int j = 0; j < 8; ++j) {
                    int rc = j * 16 + laneL;
                    int row = isA ? (m0 + rc <= Mm1 ? m0 + rc : Mm1) : rc;
                    const unsigned short* gp = plane + (size_t)row * 128 + kt * 32 + laneH * 8;
                    unsigned short* lp = &lds[(w * 8 + j) * 512];
                    gload_lds16(gp, lp);
                }
            }
            __syncthreads();

            const bf16x8* fr = (const bf16x8*)lds;
            bf16x8 ah[4], al[4], bh[4], bl[4];
            #pragma unroll
            for (int mi = 0; mi < 4; ++mi)
                ah[mi] = fr[(0 + wi * 4 + mi) * 64 + lane];
            if (hasAlo) {
                #pragma unroll
                for (int mi = 0; mi < 4; ++mi)
                    al[mi] = fr[(8 + wi * 4 + mi) * 64 + lane];
            }
            #pragma unroll
            for (int nj = 0; nj < 4; ++nj)
                bh[nj] = fr[(16 + wj * 4 + nj) * 64 + lane];
            if (hasBlo) {
                #pragma unroll
                for (int nj = 0; nj < 4; ++nj)
                    bl[nj] = fr[(24 + wj * 4 + nj) * 64 + lane];
            }
            #pragma unroll
            for (int mi = 0; mi < 4; ++mi)
                #pragma unroll
                for (int nj = 0; nj < 4; ++nj) {
                    acc[mi][nj] = __builtin_amdgcn_mfma_f32_16x16x32_bf16(
                        ah[mi], bh[nj], acc[mi][nj], 0, 0, 0);
                    if (hasBlo)
                        acc[mi][nj] = __builtin_amdgcn_mfma_f32_16x16x32_bf16(
                            ah[mi], bl[nj], acc[mi][nj], 0, 0, 0);
                    if (hasAlo)
                        acc[mi][nj] = __builtin_amdgcn_mfma_f32_16x16x32_bf16(
                            al[mi], bh[nj], acc[mi][nj], 0, 0, 0);
                }
            __syncthreads();
        }
    }

    const bool hasPrelu = (g.prelu != nullptr);
    const bool outF32 = (g.Cf != nullptr);
    #pragma unroll
    for (int nj = 0; nj < 4; ++nj) {
        int col = wj * 64 + nj * 16 + laneL;
        float bv = g.bias[col];
        float av = hasPrelu ? g.prelu[col] : 0.f;
        #pragma unroll
        for (int mi = 0; mi < 4; ++mi) {
            #pragma unroll
            for (int r = 0; r < 4; ++r) {
                int m = m0 + wi * 64 + mi * 16 + laneH * 4 + r;
                if (m >= g.M) continue;
                float v = acc[mi][nj][r] + bv;
                if (hasPrelu) v = v >= 0.f ? v : av * v;
                size_t idx = (size_t)m * 128 + col;
                if (outF32) {
                    g.Cf[idx] = v;
                } else {
                    unsigned short h = f2bf(v);
                    g.C_hi[idx] = h;
                    g.C_lo[idx] = f2bf(v - bf2f(h));
                }
            }
        }
    }
}

extern "C" void kernel_launch(void* const* d_in, const int* in_sizes, int n_in,
                              void* d_out, int out_size, void* d_ws, size_t ws_size,
                              hipStream_t stream) {
    const float* x      = (const float*)d_in[0];
    const int*   ei     = (const int*)d_in[1];
    const int*   et     = (const int*)d_in[2];
    const float* Wnum   = (const float*)d_in[3];
    const float* bnum   = (const float*)d_in[4];
    const float* Wcat   = (const float*)d_in[5];
    const float* bcat   = (const float*)d_in[6];
    const float* Win    = (const float*)d_in[7];
    const float* bin    = (const float*)d_in[8];
    const float* pa     = (const float*)d_in[9];
    const float* Wrel1  = (const float*)d_in[10];
    const float* Wroot1 = (const float*)d_in[11];
    const float* brg1   = (const float*)d_in[12];
    const float* Wrel2  = (const float*)d_in[13];
    const float* Wroot2 = (const float*)d_in[14];
    const float* brg2   = (const float*)d_in[15];
    const float* Wcls   = (const float*)d_in[16];
    const float* bcls   = (const float*)d_in[17];
    float* out = (float*)d_out;

    const int N = in_sizes[0] / 8;
    const int E = in_sizes[1] / 2;
    const int nseg = 2 * N;
    const size_t NH = (size_t)N * 128;

    char* w = (char*)d_ws;
    unsigned short* h0_hi = (unsigned short*)w;  w += NH * 2;
    unsigned short* h0_lo = (unsigned short*)w;  w += NH * 2;
    unsigned short* agg_hi = (unsigned short*)w; w += 2 * NH * 2;
    int* deg  = (int*)w;  w += (size_t)nseg * 4;
    int* off  = (int*)w;  w += (size_t)nseg * 4;
    int* rank = (int*)w;  w += (size_t)E * 4;
    int* esrc = (int*)w;  w += (size_t)E * 4;
    int* bsum = (int*)w;  w += 1024 * 4;
    unsigned short* wplanes = (unsigned short*)w;  w += 8 * 2 * 16384 * 2;

    unsigned short* hp_hi = agg_hi;
    unsigned short* hp_lo = agg_hi + NH;
    unsigned short* h1_hi = (unsigned short*)d_out;
    unsigned short* h1_lo = h1_hi + NH;
    unsigned short* h2_hi = h0_hi;
    unsigned short* h2_lo = h0_lo;

    unsigned short* whi[8];
    unsigned short* wlo[8];
    for (int i = 0; i < 8; ++i) {
        whi[i] = wplanes + (size_t)i * 2 * 16384;
        wlo[i] = whi[i] + 16384;
    }

    hipMemsetAsync(deg, 0, (size_t)nseg * sizeof(int), stream);

    {
        WArgs a;
        a.W[0] = Win;   a.W[1] = Wroot1; a.W[2] = Wrel1; a.W[3] = Wrel1 + 16384;
        a.W[4] = Wroot2; a.W[5] = Wrel2; a.W[6] = Wrel2 + 16384; a.W[7] = Wcls;
        for (int i = 0; i < 8; ++i) { a.hi[i] = whi[i]; a.lo[i] = wlo[i]; }
        k_wsplit<<<dim3(64, 8), 256, 0, stream>>>(a);
    }

    const int nb = (nseg + 255) / 256;
    const int gE8 = (E + 2047) / 2048;
    const int gm = (N + 127) / 128;
    const int gg = (nseg + 7) / 8;

    k_pre<<<(N * 128 + 255) / 256, 256, 0, stream>>>(x, Wnum, bnum, Wcat, bcat, hp_hi, hp_lo, N);
    k_rank<<<gE8, 256, 0, stream>>>(ei, et, deg, rank, E, N);
    k_scan1<<<nb, 256, 0, stream>>>(deg, off, bsum, nseg);
    k_scan2<<<1, 1024, 0, stream>>>(bsum, nb);
    k_scan3<<<nb, 256, 0, stream>>>(off, bsum, nseg);
    k_scatter<<<gE8, 256, 0, stream>>>(ei, et, off, rank, esrc, E, N);

    // embed
    {
        GArgs g = {};
        g.A_hi[0] = hp_hi; g.A_lo[0] = hp_lo; g.alo[0] = 1; g.blo[0] = 1;
        g.B_hi[0] = whi[0]; g.B_lo[0] = wlo[0];
        g.bias = bin; g.prelu = pa;
        g.Cf = nullptr; g.C_hi = h0_hi; g.C_lo = h0_lo;
        g.M = N; g.P = 1;
        k_mgemm<<<gm, 256, 0, stream>>>(g);
    }
    // layer 1
    k_gather<<<gg, 256, 0, stream>>>(h0_hi, esrc, off, deg, agg_hi, nseg);
    {
        GArgs g = {};
        g.A_hi[0] = h0_hi;       g.A_lo[0] = h0_lo;  g.alo[0] = 1; g.blo[0] = 1;
        g.A_hi[1] = agg_hi;      g.alo[1] = 0;       g.blo[1] = 0;
        g.A_hi[2] = agg_hi + NH; g.alo[2] = 0;       g.blo[2] = 0;
        g.B_hi[0] = whi[1]; g.B_lo[0] = wlo[1];
        g.B_hi[1] = whi[2]; g.B_lo[1] = wlo[2];
        g.B_hi[2] = whi[3]; g.B_lo[2] = wlo[3];
        g.bias = brg1; g.prelu = nullptr;
        g.Cf = nullptr; g.C_hi = h1_hi; g.C_lo = h1_lo;
        g.M = N; g.P = 3;
        k_mgemm<<<gm, 256, 0, stream>>>(g);
    }
    // layer 2
    k_gather<<<gg, 256, 0, stream>>>(h1_hi, esrc, off, deg, agg_hi, nseg);
    {
        GArgs g = {};
        g.A_hi[0] = h1_hi;       g.A_lo[0] = h1_lo;  g.alo[0] = 1; g.blo[0] = 1;
        g.A_hi[1] = agg_hi;      g.alo[1] = 0;       g.blo[1] = 0;
        g.A_hi[2] = agg_hi + NH; g.alo[2] = 0;       g.blo[2] = 0;
        g.B_hi[0] = whi[4]; g.B_lo[0] = wlo[4];
        g.B_hi[1] = whi[5]; g.B_lo[1] = wlo[5];
        g.B_hi[2] = whi[6]; g.B_lo[2] = wlo[6];
        g.bias = brg2; g.prelu = nullptr;
        g.Cf = nullptr; g.C_hi = h2_hi; g.C_lo = h2_lo;
        g.M = N; g.P = 3;
        k_mgemm<<<gm, 256, 0, stream>>>(g);
    }
    // classifier
    {
        GArgs g = {};
        g.A_hi[0] = h2_hi; g.A_lo[0] = h2_lo; g.alo[0] = 1; g.blo[0] = 1;
        g.B_hi[0] = whi[7]; g.B_lo[0] = wlo[7];
        g.bias = bcls; g.prelu = nullptr;
        g.Cf = out; g.C_hi = nullptr; g.C_lo = nullptr;
        g.M = N; g.P = 1;
        k_mgemm<<<gm, 256, 0, stream>>>(g);
    }
}

// Round 7
// 550.037 us; speedup vs baseline: 1.9071x; 1.1077x over previous
//
#include <hip/hip_runtime.h>
#include <cstdint>

// ---------------------------------------------------------------------------
// BotRGCN round 7: pipelined double-buffered MFMA GEMM (1 barrier/step,
// prefetch overlaps compute) + LDS-staged coalesced epilogue (kills 2x write
// amplification). Gather + CSR unchanged from round 6.
// ---------------------------------------------------------------------------

typedef short bf16x8 __attribute__((ext_vector_type(8)));
typedef float f32x4  __attribute__((ext_vector_type(4)));

__device__ __forceinline__ unsigned short f2bf(float f) {
    unsigned int u = __builtin_bit_cast(unsigned int, f);
    u += 0x7fff + ((u >> 16) & 1);          // RNE
    return (unsigned short)(u >> 16);
}
__device__ __forceinline__ float bf2f(unsigned short h) {
    unsigned int u = ((unsigned int)h) << 16;
    return __builtin_bit_cast(float, u);
}
__device__ __forceinline__ float lo16f(unsigned int u) {
    return __builtin_bit_cast(float, u << 16);
}
__device__ __forceinline__ float hi16f(unsigned int u) {
    return __builtin_bit_cast(float, u & 0xffff0000u);
}

__device__ __forceinline__ void gload_lds16(const void* g, void* l) {
    __builtin_amdgcn_global_load_lds(
        (const __attribute__((address_space(1))) void*)g,
        (__attribute__((address_space(3))) void*)l, 16, 0, 0);
}

// ---- feature pre-embed into hi/lo planes ----
__global__ __launch_bounds__(256) void k_pre(
    const float* __restrict__ x,
    const float* __restrict__ Wnum, const float* __restrict__ bnum,
    const float* __restrict__ Wcat, const float* __restrict__ bcat,
    unsigned short* __restrict__ hi, unsigned short* __restrict__ lo, int N)
{
    int gid = blockIdx.x * 256 + threadIdx.x;
    if (gid >= N * 128) return;
    int n = gid >> 7, k = gid & 127;
    const float* xr = x + n * 8;
    float acc;
    if (k < 64) {
        acc = bnum[k];
        #pragma unroll
        for (int p = 0; p < 5; ++p) acc += xr[p] * Wnum[p * 64 + k];
    } else {
        int kk = k - 64;
        acc = bcat[kk];
        #pragma unroll
        for (int p = 0; p < 3; ++p) acc += xr[5 + p] * Wcat[p * 64 + kk];
    }
    float v = acc >= 0.f ? acc : 0.01f * acc;
    unsigned short h = f2bf(v);
    hi[gid] = h;
    lo[gid] = f2bf(v - bf2f(h));
}

// ---- weight split+transpose ----
struct WArgs {
    const float* W[8];
    unsigned short* hi[8];
    unsigned short* lo[8];
};
__global__ __launch_bounds__(256) void k_wsplit(WArgs a)
{
    int part = blockIdx.y;
    int idx = blockIdx.x * 256 + threadIdx.x;
    int n = idx >> 7, k = idx & 127;
    float v = a.W[part][(size_t)k * 128 + n];
    unsigned short h = f2bf(v);
    a.hi[part][(size_t)n * 128 + k] = h;
    a.lo[part][(size_t)n * 128 + k] = f2bf(v - bf2f(h));
}

// ---- CSR build: rank pass (8 edges/thread) ----
__global__ __launch_bounds__(256) void k_rank(
    const int* __restrict__ ei, const int* __restrict__ et,
    int* __restrict__ deg, int* __restrict__ rank, int E, int N)
{
    int base = blockIdx.x * 2048 + threadIdx.x;
    int e[8], r[8];
    #pragma unroll
    for (int j = 0; j < 8; ++j) {
        e[j] = base + j * 256;
        r[j] = 0;
        if (e[j] < E) r[j] = atomicAdd(&deg[et[e[j]] * N + ei[E + e[j]]], 1);
    }
    #pragma unroll
    for (int j = 0; j < 8; ++j)
        if (e[j] < E) rank[e[j]] = r[j];
}

__global__ __launch_bounds__(256) void k_scan1(
    const int* __restrict__ deg, int* __restrict__ off,
    int* __restrict__ bsum, int n)
{
    __shared__ int s[256];
    int t = threadIdx.x;
    int i = blockIdx.x * 256 + t;
    int v = (i < n) ? deg[i] : 0;
    s[t] = v;
    __syncthreads();
    #pragma unroll
    for (int d = 1; d < 256; d <<= 1) {
        int add = (t >= d) ? s[t - d] : 0;
        __syncthreads();
        s[t] += add;
        __syncthreads();
    }
    if (i < n) off[i] = s[t] - v;
    if (t == 255) bsum[blockIdx.x] = s[255];
}

__global__ __launch_bounds__(1024) void k_scan2(int* __restrict__ bsum, int nb)
{
    __shared__ int s[1024];
    int t = threadIdx.x;
    int v = (t < nb) ? bsum[t] : 0;
    s[t] = v;
    __syncthreads();
    #pragma unroll
    for (int d = 1; d < 1024; d <<= 1) {
        int add = (t >= d) ? s[t - d] : 0;
        __syncthreads();
        s[t] += add;
        __syncthreads();
    }
    if (t < nb) bsum[t] = s[t] - v;
}

__global__ __launch_bounds__(256) void k_scan3(
    int* __restrict__ off, const int* __restrict__ bsum, int n)
{
    int i = blockIdx.x * 256 + threadIdx.x;
    if (i < n) off[i] += bsum[blockIdx.x];
}

// ---- CSR build: atomic-free scatter (8 edges/thread) ----
__global__ __launch_bounds__(256) void k_scatter(
    const int* __restrict__ ei, const int* __restrict__ et,
    const int* __restrict__ off, const int* __restrict__ rank,
    int* __restrict__ esrc, int E, int N)
{
    int base = blockIdx.x * 2048 + threadIdx.x;
    #pragma unroll
    for (int j = 0; j < 8; ++j) {
        int e = base + j * 256;
        if (e < E) {
            int seg = et[e] * N + ei[E + e];
            esrc[off[seg] + rank[e]] = ei[e];
        }
    }
}

// ---- mean aggregation, bf16 hi plane, quarter-wave rows ----
__global__ __launch_bounds__(256) void k_gather(
    const unsigned short* __restrict__ h_hi,
    const int* __restrict__ esrc,
    const int* __restrict__ off, const int* __restrict__ deg,
    unsigned short* __restrict__ a_hi, int nseg)
{
    int i = blockIdx.x * 8 + (threadIdx.x >> 5);
    if (i >= nseg) return;
    int l32 = threadIdx.x & 31;
    int q = l32 >> 4;
    int l16 = l32 & 15;
    int cnt = deg[i], st = off[i];
    const uint4* hp = (const uint4*)h_hi;
    float a0 = 0.f, a1 = 0.f, a2 = 0.f, a3 = 0.f;
    float a4 = 0.f, a5 = 0.f, a6 = 0.f, a7 = 0.f;
    int e = q;
    for (; e + 6 < cnt; e += 8) {
        int i0 = esrc[st + e + 0];
        int i1 = esrc[st + e + 2];
        int i2 = esrc[st + e + 4];
        int i3 = esrc[st + e + 6];
        uint4 u0 = hp[(size_t)i0 * 16 + l16];
        uint4 u1 = hp[(size_t)i1 * 16 + l16];
        uint4 u2 = hp[(size_t)i2 * 16 + l16];
        uint4 u3 = hp[(size_t)i3 * 16 + l16];
        a0 += lo16f(u0.x); a1 += hi16f(u0.x); a2 += lo16f(u0.y); a3 += hi16f(u0.y);
        a4 += lo16f(u0.z); a5 += hi16f(u0.z); a6 += lo16f(u0.w); a7 += hi16f(u0.w);
        a0 += lo16f(u1.x); a1 += hi16f(u1.x); a2 += lo16f(u1.y); a3 += hi16f(u1.y);
        a4 += lo16f(u1.z); a5 += hi16f(u1.z); a6 += lo16f(u1.w); a7 += hi16f(u1.w);
        a0 += lo16f(u2.x); a1 += hi16f(u2.x); a2 += lo16f(u2.y); a3 += hi16f(u2.y);
        a4 += lo16f(u2.z); a5 += hi16f(u2.z); a6 += lo16f(u2.w); a7 += hi16f(u2.w);
        a0 += lo16f(u3.x); a1 += hi16f(u3.x); a2 += lo16f(u3.y); a3 += hi16f(u3.y);
        a4 += lo16f(u3.z); a5 += hi16f(u3.z); a6 += lo16f(u3.w); a7 += hi16f(u3.w);
    }
    for (; e < cnt; e += 2) {
        uint4 u = hp[(size_t)esrc[st + e] * 16 + l16];
        a0 += lo16f(u.x); a1 += hi16f(u.x); a2 += lo16f(u.y); a3 += hi16f(u.y);
        a4 += lo16f(u.z); a5 += hi16f(u.z); a6 += lo16f(u.w); a7 += hi16f(u.w);
    }
    a0 += __shfl_xor(a0, 16, 64);
    a1 += __shfl_xor(a1, 16, 64);
    a2 += __shfl_xor(a2, 16, 64);
    a3 += __shfl_xor(a3, 16, 64);
    a4 += __shfl_xor(a4, 16, 64);
    a5 += __shfl_xor(a5, 16, 64);
    a6 += __shfl_xor(a6, 16, 64);
    a7 += __shfl_xor(a7, 16, 64);
    if (q == 0) {
        float inv = 1.0f / (float)(cnt > 1 ? cnt : 1);
        uint4 o;
        o.x = (unsigned int)f2bf(a0 * inv) | ((unsigned int)f2bf(a1 * inv) << 16);
        o.y = (unsigned int)f2bf(a2 * inv) | ((unsigned int)f2bf(a3 * inv) << 16);
        o.z = (unsigned int)f2bf(a4 * inv) | ((unsigned int)f2bf(a5 * inv) << 16);
        o.w = (unsigned int)f2bf(a6 * inv) | ((unsigned int)f2bf(a7 * inv) << 16);
        ((uint4*)a_hi)[(size_t)i * 16 + l16] = o;
    }
}

// ---- pipelined split-bf16 MFMA GEMM ----
// Steps s = p*4 + kt over (part, k-tile). Per step: stage up to 4 plane-tiles
// (Ah, Al, Bh, Bl; 8 KB each) into one of two 32 KB LDS buffers. Pipeline:
// barrier -> prefetch step s+1 into other buffer -> compute step s.
// Epilogue: acc -> LDS (C layout) -> coalesced uint4 global stores.
struct GArgs {
    const unsigned short* A_hi[3];
    const unsigned short* A_lo[3];
    const unsigned short* B_hi[3];   // transposed [n][k]
    const unsigned short* B_lo[3];
    int alo[3];
    int blo[3];
    const float* bias;
    const float* prelu;
    float* Cf;                       // if non-null: fp32 output
    unsigned short* C_hi;
    unsigned short* C_lo;
    int M;
    int P;
};

__global__ __launch_bounds__(256) void k_mgemm(GArgs g)
{
    __shared__ unsigned short lds[2][32 * 512];   // 2 x 32 KB
    const int t = threadIdx.x;
    const int w = t >> 6, lane = t & 63;
    const int laneL = lane & 15, laneH = lane >> 4;
    const int wi = w >> 1, wj = w & 1;
    const int m0 = blockIdx.x * 128;
    const int Mm1 = g.M - 1;
    const int S = g.P * 4;

    f32x4 acc[4][4];
    #pragma unroll
    for (int a = 0; a < 4; ++a)
        #pragma unroll
        for (int b = 0; b < 4; ++b)
            acc[a][b] = (f32x4){0.f, 0.f, 0.f, 0.f};

    // stage step s into buffer buf: 32 chunks (tile slot*8 + j), round-robin by wave
    auto stage = [&](int s, unsigned short* buf) {
        int p = s >> 2, koff = (s & 3) * 32;
        const unsigned short* tp[4];
        tp[0] = g.A_hi[p];
        tp[1] = g.alo[p] ? g.A_lo[p] : nullptr;
        tp[2] = g.B_hi[p];
        tp[3] = g.blo[p] ? g.B_lo[p] : nullptr;
        #pragma unroll
        for (int c = 0; c < 8; ++c) {
            int chunk = w + c * 4;            // 0..31
            int slot = chunk >> 3, j = chunk & 7;
            const unsigned short* plane = tp[slot];
            if (!plane) continue;
            int rc = j * 16 + laneL;
            int row = (slot < 2) ? (m0 + rc <= Mm1 ? m0 + rc : Mm1) : rc;
            const unsigned short* gp = plane + (size_t)row * 128 + koff + laneH * 8;
            gload_lds16(gp, &buf[(slot * 8 + j) * 512]);
        }
    };

    stage(0, lds[0]);
    for (int s = 0; s < S; ++s) {
        unsigned short* cur = lds[s & 1];
        unsigned short* nxt = lds[(s & 1) ^ 1];
        __syncthreads();                      // drains stage(s); frees nxt
        if (s + 1 < S) stage(s + 1, nxt);     // overlaps with compute below
        int p = s >> 2;
        const bool hasAlo = g.alo[p] != 0;
        const bool hasBlo = g.blo[p] != 0;
        const bf16x8* fr = (const bf16x8*)cur;
        bf16x8 ah[4], al[4], bh[4], bl[4];
        #pragma unroll
        for (int mi = 0; mi < 4; ++mi)
            ah[mi] = fr[(0 + wi * 4 + mi) * 64 + lane];
        if (hasAlo) {
            #pragma unroll
            for (int mi = 0; mi < 4; ++mi)
                al[mi] = fr[(8 + wi * 4 + mi) * 64 + lane];
        }
        #pragma unroll
        for (int nj = 0; nj < 4; ++nj)
            bh[nj] = fr[(16 + wj * 4 + nj) * 64 + lane];
        if (hasBlo) {
            #pragma unroll
            for (int nj = 0; nj < 4; ++nj)
                bl[nj] = fr[(24 + wj * 4 + nj) * 64 + lane];
        }
        #pragma unroll
        for (int mi = 0; mi < 4; ++mi)
            #pragma unroll
            for (int nj = 0; nj < 4; ++nj) {
                acc[mi][nj] = __builtin_amdgcn_mfma_f32_16x16x32_bf16(
                    ah[mi], bh[nj], acc[mi][nj], 0, 0, 0);
                if (hasBlo)
                    acc[mi][nj] = __builtin_amdgcn_mfma_f32_16x16x32_bf16(
                        ah[mi], bl[nj], acc[mi][nj], 0, 0, 0);
                if (hasAlo)
                    acc[mi][nj] = __builtin_amdgcn_mfma_f32_16x16x32_bf16(
                        al[mi], bh[nj], acc[mi][nj], 0, 0, 0);
            }
    }

    // ---- epilogue: acc -> LDS (C layout) -> coalesced stores ----
    const bool hasPrelu = (g.prelu != nullptr);
    float bv[4], av[4];
    #pragma unroll
    for (int nj = 0; nj < 4; ++nj) {
        int col = wj * 64 + nj * 16 + laneL;
        bv[nj] = g.bias[col];
        av[nj] = hasPrelu ? g.prelu[col] : 0.f;
    }

    if (g.Cf) {
        // fp32 output: 128x128 f32 = 64 KB (both buffers)
        float* lf = (float*)&lds[0][0];
        __syncthreads();
        #pragma unroll
        for (int nj = 0; nj < 4; ++nj) {
            int col = wj * 64 + nj * 16 + laneL;
            #pragma unroll
            for (int mi = 0; mi < 4; ++mi)
                #pragma unroll
                for (int r = 0; r < 4; ++r) {
                    int row = wi * 64 + mi * 16 + laneH * 4 + r;
                    float v = acc[mi][nj][r] + bv[nj];
                    lf[row * 128 + col] = v;
                }
        }
        __syncthreads();
        const uint4* lsrc = (const uint4*)lf;
        #pragma unroll
        for (int it = 0; it < 16; ++it) {
            int idx = it * 256 + t;          // 4096 uint4
            int row = idx >> 5, c = idx & 31;
            int m = m0 + row;
            if (m < g.M)
                ((uint4*)(g.Cf + (size_t)m * 128))[c] = lsrc[idx];
        }
    } else {
        unsigned short* lp = &lds[0][0];     // 128x128 ushort = 32 KB
        // hi pass
        __syncthreads();
        #pragma unroll
        for (int nj = 0; nj < 4; ++nj) {
            int col = wj * 64 + nj * 16 + laneL;
            #pragma unroll
            for (int mi = 0; mi < 4; ++mi)
                #pragma unroll
                for (int r = 0; r < 4; ++r) {
                    int row = wi * 64 + mi * 16 + laneH * 4 + r;
                    float v = acc[mi][nj][r] + bv[nj];
                    if (hasPrelu) v = v >= 0.f ? v : av[nj] * v;
                    lp[row * 128 + col] = f2bf(v);
                }
        }
        __syncthreads();
        {
            const uint4* lsrc = (const uint4*)lp;
            #pragma unroll
            for (int it = 0; it < 8; ++it) {
                int idx = it * 256 + t;      // 2048 uint4
                int row = idx >> 4, c = idx & 15;
                int m = m0 + row;
                if (m < g.M)
                    ((uint4*)(g.C_hi + (size_t)m * 128))[c] = lsrc[idx];
            }
        }
        // lo pass
        __syncthreads();
        #pragma unroll
        for (int nj = 0; nj < 4; ++nj) {
            int col = wj * 64 + nj * 16 + laneL;
            #pragma unroll
            for (int mi = 0; mi < 4; ++mi)
                #pragma unroll
                for (int r = 0; r < 4; ++r) {
                    int row = wi * 64 + mi * 16 + laneH * 4 + r;
                    float v = acc[mi][nj][r] + bv[nj];
                    if (hasPrelu) v = v >= 0.f ? v : av[nj] * v;
                    unsigned short h = f2bf(v);
                    lp[row * 128 + col] = f2bf(v - bf2f(h));
                }
        }
        __syncthreads();
        {
            const uint4* lsrc = (const uint4*)lp;
            #pragma unroll
            for (int it = 0; it < 8; ++it) {
                int idx = it * 256 + t;
                int row = idx >> 4, c = idx & 15;
                int m = m0 + row;
                if (m < g.M)
                    ((uint4*)(g.C_lo + (size_t)m * 128))[c] = lsrc[idx];
            }
        }
    }
}

extern "C" void kernel_launch(void* const* d_in, const int* in_sizes, int n_in,
                              void* d_out, int out_size, void* d_ws, size_t ws_size,
                              hipStream_t stream) {
    const float* x      = (const float*)d_in[0];
    const int*   ei     = (const int*)d_in[1];
    const int*   et     = (const int*)d_in[2];
    const float* Wnum   = (const float*)d_in[3];
    const float* bnum   = (const float*)d_in[4];
    const float* Wcat   = (const float*)d_in[5];
    const float* bcat   = (const float*)d_in[6];
    const float* Win    = (const float*)d_in[7];
    const float* bin    = (const float*)d_in[8];
    const float* pa     = (const float*)d_in[9];
    const float* Wrel1  = (const float*)d_in[10];
    const float* Wroot1 = (const float*)d_in[11];
    const float* brg1   = (const float*)d_in[12];
    const float* Wrel2  = (const float*)d_in[13];
    const float* Wroot2 = (const float*)d_in[14];
    const float* brg2   = (const float*)d_in[15];
    const float* Wcls   = (const float*)d_in[16];
    const float* bcls   = (const float*)d_in[17];
    float* out = (float*)d_out;

    const int N = in_sizes[0] / 8;
    const int E = in_sizes[1] / 2;
    const int nseg = 2 * N;
    const size_t NH = (size_t)N * 128;

    char* w = (char*)d_ws;
    unsigned short* h0_hi = (unsigned short*)w;  w += NH * 2;
    unsigned short* h0_lo = (unsigned short*)w;  w += NH * 2;
    unsigned short* agg_hi = (unsigned short*)w; w += 2 * NH * 2;
    int* deg  = (int*)w;  w += (size_t)nseg * 4;
    int* off  = (int*)w;  w += (size_t)nseg * 4;
    int* rank = (int*)w;  w += (size_t)E * 4;
    int* esrc = (int*)w;  w += (size_t)E * 4;
    int* bsum = (int*)w;  w += 1024 * 4;
    unsigned short* wplanes = (unsigned short*)w;  w += 8 * 2 * 16384 * 2;

    unsigned short* hp_hi = agg_hi;
    unsigned short* hp_lo = agg_hi + NH;
    unsigned short* h1_hi = (unsigned short*)d_out;
    unsigned short* h1_lo = h1_hi + NH;
    unsigned short* h2_hi = h0_hi;
    unsigned short* h2_lo = h0_lo;

    unsigned short* whi[8];
    unsigned short* wlo[8];
    for (int i = 0; i < 8; ++i) {
        whi[i] = wplanes + (size_t)i * 2 * 16384;
        wlo[i] = whi[i] + 16384;
    }

    hipMemsetAsync(deg, 0, (size_t)nseg * sizeof(int), stream);

    {
        WArgs a;
        a.W[0] = Win;   a.W[1] = Wroot1; a.W[2] = Wrel1; a.W[3] = Wrel1 + 16384;
        a.W[4] = Wroot2; a.W[5] = Wrel2; a.W[6] = Wrel2 + 16384; a.W[7] = Wcls;
        for (int i = 0; i < 8; ++i) { a.hi[i] = whi[i]; a.lo[i] = wlo[i]; }
        k_wsplit<<<dim3(64, 8), 256, 0, stream>>>(a);
    }

    const int nb = (nseg + 255) / 256;
    const int gE8 = (E + 2047) / 2048;
    const int gm = (N + 127) / 128;
    const int gg = (nseg + 7) / 8;

    k_pre<<<(N * 128 + 255) / 256, 256, 0, stream>>>(x, Wnum, bnum, Wcat, bcat, hp_hi, hp_lo, N);
    k_rank<<<gE8, 256, 0, stream>>>(ei, et, deg, rank, E, N);
    k_scan1<<<nb, 256, 0, stream>>>(deg, off, bsum, nseg);
    k_scan2<<<1, 1024, 0, stream>>>(bsum, nb);
    k_scan3<<<nb, 256, 0, stream>>>(off, bsum, nseg);
    k_scatter<<<gE8, 256, 0, stream>>>(ei, et, off, rank, esrc, E, N);

    // embed
    {
        GArgs g = {};
        g.A_hi[0] = hp_hi; g.A_lo[0] = hp_lo; g.alo[0] = 1; g.blo[0] = 1;
        g.B_hi[0] = whi[0]; g.B_lo[0] = wlo[0];
        g.bias = bin; g.prelu = pa;
        g.Cf = nullptr; g.C_hi = h0_hi; g.C_lo = h0_lo;
        g.M = N; g.P = 1;
        k_mgemm<<<gm, 256, 0, stream>>>(g);
    }
    // layer 1
    k_gather<<<gg, 256, 0, stream>>>(h0_hi, esrc, off, deg, agg_hi, nseg);
    {
        GArgs g = {};
        g.A_hi[0] = h0_hi;       g.A_lo[0] = h0_lo;  g.alo[0] = 1; g.blo[0] = 1;
        g.A_hi[1] = agg_hi;      g.alo[1] = 0;       g.blo[1] = 0;
        g.A_hi[2] = agg_hi + NH; g.alo[2] = 0;       g.blo[2] = 0;
        g.B_hi[0] = whi[1]; g.B_lo[0] = wlo[1];
        g.B_hi[1] = whi[2]; g.B_lo[1] = wlo[2];
        g.B_hi[2] = whi[3]; g.B_lo[2] = wlo[3];
        g.bias = brg1; g.prelu = nullptr;
        g.Cf = nullptr; g.C_hi = h1_hi; g.C_lo = h1_lo;
        g.M = N; g.P = 3;
        k_mgemm<<<gm, 256, 0, stream>>>(g);
    }
    // layer 2
    k_gather<<<gg, 256, 0, stream>>>(h1_hi, esrc, off, deg, agg_hi, nseg);
    {
        GArgs g = {};
        g.A_hi[0] = h1_hi;       g.A_lo[0] = h1_lo;  g.alo[0] = 1; g.blo[0] = 1;
        g.A_hi[1] = agg_hi;      g.alo[1] = 0;       g.blo[1] = 0;
        g.A_hi[2] = agg_hi + NH; g.alo[2] = 0;       g.blo[2] = 0;
        g.B_hi[0] = whi[4]; g.B_lo[0] = wlo[4];
        g.B_hi[1] = whi[5]; g.B_lo[1] = wlo[5];
        g.B_hi[2] = whi[6]; g.B_lo[2] = wlo[6];
        g.bias = brg2; g.prelu = nullptr;
        g.Cf = nullptr; g.C_hi = h2_hi; g.C_lo = h2_lo;
        g.M = N; g.P = 3;
        k_mgemm<<<gm, 256, 0, stream>>>(g);
    }
    // classifier
    {
        GArgs g = {};
        g.A_hi[0] = h2_hi; g.A_lo[0] = h2_lo; g.alo[0] = 1; g.blo[0] = 1;
        g.B_hi[0] = whi[7]; g.B_lo[0] = wlo[7];
        g.bias = bcls; g.prelu = nullptr;
        g.Cf = out; g.C_hi = nullptr; g.C_lo = nullptr;
        g.M = N; g.P = 1;
        k_mgemm<<<gm, 256, 0, stream>>>(g);
    }
}